// Round 12
// baseline (193.319 us; speedup 1.0000x reference)
//
#include <hip/hip_runtime.h>
#include <math.h>
#include <stdint.h>

#define NN 500000   // nodes
#define NB 4096     // segments
#define DD 256      // feature dim

typedef short  short8  __attribute__((ext_vector_type(8)));
typedef short  short4v __attribute__((ext_vector_type(4)));
typedef float  floatx4 __attribute__((ext_vector_type(4)));
typedef float  f2      __attribute__((ext_vector_type(2)));

typedef const __attribute__((address_space(1))) unsigned int g_u32;
typedef       __attribute__((address_space(3))) unsigned int l_u32;

__device__ __forceinline__ f2 sp(float v) { return (f2){v, v}; }

// fp32 -> bf16 round-to-nearest-even
__device__ __forceinline__ short f2bf(float f) {
    uint32_t u = __float_as_uint(f);
    u += 0x7fffu + ((u >> 16) & 1u);
    return (short)(u >> 16);
}

// Packed gelu via A&S 7.1.28: erf(z) = 1 - (1+a1 z+..+a6 z^6)^-16, |eps|<=3e-7.
__device__ __forceinline__ f2 gelu2(f2 x) {
    f2 z = __builtin_elementwise_abs(x) * sp(0.70710678118654752440f);
    f2 p = __builtin_elementwise_fma(z, sp(0.0000430638f), sp(0.0002765672f));
    p = __builtin_elementwise_fma(p, z, sp(0.0001520143f));
    p = __builtin_elementwise_fma(p, z, sp(0.0092705272f));
    p = __builtin_elementwise_fma(p, z, sp(0.0422820123f));
    p = __builtin_elementwise_fma(p, z, sp(0.0705230784f));
    p = __builtin_elementwise_fma(p, z, sp(1.0f));
    p = p * p; p = p * p; p = p * p; p = p * p;           // p^16
    f2 r = { __builtin_amdgcn_rcpf(p.x), __builtin_amdgcn_rcpf(p.y) };
    f2 er = __builtin_elementwise_copysign(sp(1.0f) - r, x);
    return sp(0.5f) * x * (sp(1.0f) + er);
}

// counted vmcnt wait (literal required in asm) + scheduling fence
__device__ __forceinline__ void wait_vmcnt(int n) {
    switch (n) {
    case 0: asm volatile("s_waitcnt vmcnt(0)" ::: "memory"); break;
    case 1: asm volatile("s_waitcnt vmcnt(1)" ::: "memory"); break;
    case 2: asm volatile("s_waitcnt vmcnt(2)" ::: "memory"); break;
    case 3: asm volatile("s_waitcnt vmcnt(3)" ::: "memory"); break;
    case 4: asm volatile("s_waitcnt vmcnt(4)" ::: "memory"); break;
    case 5: asm volatile("s_waitcnt vmcnt(5)" ::: "memory"); break;
    case 6: asm volatile("s_waitcnt vmcnt(6)" ::: "memory"); break;
    default: asm volatile("s_waitcnt vmcnt(7)" ::: "memory"); break;
    }
    __builtin_amdgcn_sched_barrier(0);
}

// ---------------------------------------------------------------------------
// Kernel 0: segment boundary precompute (unchanged).
// ---------------------------------------------------------------------------
__global__ __launch_bounds__(256) void seg_bounds(
    const int* __restrict__ seg, int* __restrict__ bnd)
{
    int i = blockIdx.x * 256 + threadIdx.x;
    if (i >= NN) return;
    int s = seg[i];
    if (i == 0) {
        for (int b = 0; b <= s; ++b) bnd[b] = 0;
    } else {
        int p = seg[i - 1];
        for (int b = p + 1; b <= s; ++b) bnd[b] = i;
    }
    if (i == NN - 1) {
        for (int b = s + 1; b <= NB; ++b) bnd[b] = NN;
    }
}

// ---------------------------------------------------------------------------
// seg kernel v5: global_load_lds ring (8 rows x 1KB per wave), explicit
// counted s_waitcnt vmcnt(N). Wave w owns a contiguous chunk of its segment;
// lane l owns cols 4l..4l+3. DMA writes lane-l 16B at slotbase + l*16 (the
// HW-fixed layout) == exactly our read layout. Zero staging VGPRs; the
// compiler has no waitcnt discretion in the stream. Math order identical to
// v4 => bitwise-same outputs.
// ---------------------------------------------------------------------------
__global__ __launch_bounds__(256) void seg_kernel(
    const float* __restrict__ x,
    const int*   __restrict__ bnd,
    const float* __restrict__ att_w,
    float* __restrict__ merged,    // (NB, 1024)
    float* __restrict__ center,    // (NB, 256)
    float* __restrict__ neighbor)  // (NB, 256)
{
    __shared__ __align__(16) float ring[4][8][256];   // 32 KB ring
    __shared__ float lds[4][4][256];                  // 16 KB combine
    __shared__ float ldsl[4][4];

    const int b   = blockIdx.x;
    const int tid = threadIdx.x;
    const int w   = tid >> 6;
    const int l   = tid & 63;

    const int start = bnd[b];
    const int end   = bnd[b + 1];

    const int cnt = end - start;
    const int q = cnt >> 2, r = cnt & 3;
    const int my_start = start + w * q + (w < r ? w : r);
    const int my_cnt   = q + (w < r ? 1 : 0);

    const float4 awv = *reinterpret_cast<const float4*>(&att_w[4 * l]);
    const f2 aw01 = {awv.x, awv.y}, aw23 = {awv.z, awv.w};
    // force att_w load completion so loop-body compiler waits don't touch it
    asm volatile("" :: "v"(awv.x), "v"(awv.y), "v"(awv.z), "v"(awv.w));
    asm volatile("s_waitcnt vmcnt(0)" ::: "memory");

    f2 c01 = sp(0.f), c23 = sp(0.f);                 // segsum(gelu)
    f2 s01 = sp(0.f), s23 = sp(0.f);                 // segsum(x)
    f2 m01 = sp(-INFINITY), m23 = sp(-INFINITY);     // segmax(x)
    f2 a01 = sp(0.f), a23 = sp(0.f);                 // sum e*x
    float lsum = 0.f;                                 // sum e (per head)

    auto process = [&](const float4& v) {
        f2 vl = {v.x, v.y}, vh = {v.z, v.w};
        f2 gl = gelu2(vl), gh = gelu2(vh);
        c01 += gl; c23 += gh;
        s01 += vl; s23 += vh;
        m01 = __builtin_elementwise_max(m01, vl);
        m23 = __builtin_elementwise_max(m23, vh);
        f2 tp = __builtin_elementwise_fma(vh, aw23, vl * aw01);
        float t = tp.x + tp.y;
        t += __shfl_xor(t, 1, 64);
        t += __shfl_xor(t, 2, 64);
        t += __shfl_xor(t, 4, 64);
        t += __shfl_xor(t, 8, 64);
        float alpha = fmaxf(t, 0.2f * t);   // leaky_relu(0.2)
        float e = __expf(alpha);            // no max-shift: |alpha| small
        lsum += e;
        f2 ev = sp(e);
        a01 = __builtin_elementwise_fma(ev, vl, a01);
        a23 = __builtin_elementwise_fma(ev, vh, a23);
    };

    auto ISSUE = [&](int row, int slot) {
        int rc = row < (NN - 1) ? row : (NN - 1);   // clamp inside x
        __builtin_amdgcn_global_load_lds(
            (g_u32*)(x + (size_t)rc * DD + 4 * l),
            (l_u32*)(&ring[w][slot][0]), 16, 0, 0);
    };

    // prologue: fill ring with up to 8 rows
    const int P = my_cnt < 8 ? my_cnt : 8;
    for (int i = 0; i < P; ++i) ISSUE(my_start + i, i);

    for (int i = 0; i < my_cnt; ++i) {
        int n = my_cnt - i - 1;                      // loads issued after row i
        wait_vmcnt(n < 7 ? n : 7);
        const int slot = i & 7;
        float4 v = *reinterpret_cast<const float4*>(&ring[w][slot][4 * l]);
        process(v);
        // v fully consumed before the slot is overwritten
        asm volatile("s_waitcnt lgkmcnt(0)" ::: "memory");
        __builtin_amdgcn_sched_barrier(0);
        const int nx = i + 8;
        if (nx < my_cnt) ISSUE(my_start + nx, slot);
    }

    // ---- cross-wave combine ----
    const int c = 4 * l;
    lds[0][w][c+0] = c01.x; lds[0][w][c+1] = c01.y; lds[0][w][c+2] = c23.x; lds[0][w][c+3] = c23.y;
    lds[1][w][c+0] = s01.x; lds[1][w][c+1] = s01.y; lds[1][w][c+2] = s23.x; lds[1][w][c+3] = s23.y;
    lds[2][w][c+0] = m01.x; lds[2][w][c+1] = m01.y; lds[2][w][c+2] = m23.x; lds[2][w][c+3] = m23.y;
    lds[3][w][c+0] = a01.x; lds[3][w][c+1] = a01.y; lds[3][w][c+2] = a23.x; lds[3][w][c+3] = a23.y;
    if ((l & 15) == 0) ldsl[w][l >> 4] = lsum;
    __syncthreads();

    const int d = tid;   // output column
    float cs = lds[0][0][d] + lds[0][1][d] + lds[0][2][d] + lds[0][3][d];
    float ss = lds[1][0][d] + lds[1][1][d] + lds[1][2][d] + lds[1][3][d];
    float mm = fmaxf(fmaxf(lds[2][0][d], lds[2][1][d]), fmaxf(lds[2][2][d], lds[2][3][d]));
    float ac = lds[3][0][d] + lds[3][1][d] + lds[3][2][d] + lds[3][3][d];
    const int h = d >> 6;
    float denom = ldsl[0][h] + ldsl[1][h] + ldsl[2][h] + ldsl[3][h];
    float att = (denom > 0.f) ? ac / denom : 0.f;
    float nm = gelu2((f2){mm, mm}).x;   // neighbor = gelu(segmax(x))

    float* mrow = merged + (size_t)b * 1024;
    mrow[256 + d] = att;
    mrow[512 + d] = mm;
    mrow[768 + d] = ss;
    center  [(size_t)b * DD + d] = cs;
    neighbor[(size_t)b * DD + d] = nm;
}

// ---------------------------------------------------------------------------
// Fused GRU GEMM v3 (unchanged from round 11)
// ---------------------------------------------------------------------------
__global__ __launch_bounds__(256) void gemm_gru(
    const float* __restrict__ center,    // (NB, 256)
    const float* __restrict__ neighbor,  // (NB, 256)
    const float* __restrict__ w_ih,      // (768, 256)
    const float* __restrict__ w_hh,      // (768, 256)
    const float* __restrict__ b_ih,      // (768)
    const float* __restrict__ b_hh,      // (768)
    float* __restrict__ merged)          // (NB, 1024)
{
    __shared__ short Ac[64 * 40];
    __shared__ short An[64 * 40];
    __shared__ short Wt[6][16 * 40];

    const int t   = threadIdx.x;
    const int w   = t >> 6, l = t & 63;
    const int m0  = blockIdx.x * 64;
    const int j0  = blockIdx.y * 16;
    const int lr  = t >> 2;
    const int lc  = (t & 3) * 8;
    const int l15 = l & 15, lq = l >> 4;

    int wg[3], wrow[3], wk4[3];
    const float* wbase[3];
    #pragma unroll
    for (int i = 0; i < 3; ++i) {
        int f = i * 256 + t;
        wg[i] = f >> 7;
        int rem2 = f & 127;
        wrow[i] = rem2 >> 3;
        wk4[i]  = rem2 & 7;
        wbase[i] = (wg[i] < 3)
            ? &w_ih[(size_t)(wg[i] * 256 + j0 + wrow[i]) * 256 + wk4[i] * 4]
            : &w_hh[(size_t)((wg[i] - 3) * 256 + j0 + wrow[i]) * 256 + wk4[i] * 4];
    }
    const float* crp = &center  [(size_t)(m0 + lr) * 256 + lc];
    const float* nrp = &neighbor[(size_t)(m0 + lr) * 256 + lc];

    floatx4 acc[6] = {};

    float4 c0 = *(const float4*)(crp),     c1 = *(const float4*)(crp + 4);
    float4 e0 = *(const float4*)(nrp),     e1 = *(const float4*)(nrp + 4);
    float4 v0 = *(const float4*)(wbase[0]);
    float4 v1 = *(const float4*)(wbase[1]);
    float4 v2 = *(const float4*)(wbase[2]);

    for (int k0 = 0; k0 < 256; k0 += 32) {
        const int kn = (k0 + 32 < 256) ? k0 + 32 : k0;
        float4 nc0 = *(const float4*)(crp + kn), nc1 = *(const float4*)(crp + kn + 4);
        float4 ne0 = *(const float4*)(nrp + kn), ne1 = *(const float4*)(nrp + kn + 4);
        float4 nv0 = *(const float4*)(wbase[0] + kn);
        float4 nv1 = *(const float4*)(wbase[1] + kn);
        float4 nv2 = *(const float4*)(wbase[2] + kn);

        short8 a8 = { f2bf(c0.x), f2bf(c0.y), f2bf(c0.z), f2bf(c0.w),
                      f2bf(c1.x), f2bf(c1.y), f2bf(c1.z), f2bf(c1.w) };
        short8 n8 = { f2bf(e0.x), f2bf(e0.y), f2bf(e0.z), f2bf(e0.w),
                      f2bf(e1.x), f2bf(e1.y), f2bf(e1.z), f2bf(e1.w) };
        short4v w40 = { f2bf(v0.x), f2bf(v0.y), f2bf(v0.z), f2bf(v0.w) };
        short4v w41 = { f2bf(v1.x), f2bf(v1.y), f2bf(v1.z), f2bf(v1.w) };
        short4v w42 = { f2bf(v2.x), f2bf(v2.y), f2bf(v2.z), f2bf(v2.w) };

        __syncthreads();
        *(short8*)&Ac[lr * 40 + lc] = a8;
        *(short8*)&An[lr * 40 + lc] = n8;
        *(short4v*)&Wt[wg[0]][wrow[0] * 40 + wk4[0] * 4] = w40;
        *(short4v*)&Wt[wg[1]][wrow[1] * 40 + wk4[1] * 4] = w41;
        *(short4v*)&Wt[wg[2]][wrow[2] * 40 + wk4[2] * 4] = w42;
        __syncthreads();

        short8 afc = *(short8*)&Ac[(w * 16 + l15) * 40 + lq * 8];
        short8 afn = *(short8*)&An[(w * 16 + l15) * 40 + lq * 8];
        #pragma unroll
        for (int gg = 0; gg < 6; ++gg) {
            short8 bf = *(short8*)&Wt[gg][l15 * 40 + lq * 8];
            acc[gg] = __builtin_amdgcn_mfma_f32_16x16x32_bf16(
                (gg < 3) ? afc : afn, bf, acc[gg], 0, 0, 0);
        }

        c0 = nc0; c1 = nc1; e0 = ne0; e1 = ne1;
        v0 = nv0; v1 = nv1; v2 = nv2;
    }

    const int col = j0 + l15;
    const float bir = b_ih[col], biz = b_ih[256 + col], bin = b_ih[512 + col];
    const float bhr = b_hh[col], bhz = b_hh[256 + col], bhn = b_hh[512 + col];
    #pragma unroll
    for (int qq = 0; qq < 4; ++qq) {
        const int row = m0 + w * 16 + lq * 4 + qq;
        float rr = 1.f / (1.f + __expf(-(acc[0][qq] + bir + acc[3][qq] + bhr)));
        float zz = 1.f / (1.f + __expf(-(acc[1][qq] + biz + acc[4][qq] + bhz)));
        float ng = tanhf(acc[2][qq] + bin + rr * (acc[5][qq] + bhn));
        float nb = neighbor[(size_t)row * 256 + col];
        merged[(size_t)row * 1024 + col] = (1.f - zz) * ng + zz * nb;
    }
}

// ---------------------------------------------------------------------------
// bf16 MFMA GEMM v3 (merge, unchanged from round 11)
// ---------------------------------------------------------------------------
__global__ __launch_bounds__(256) void gemm_bf16(
    const float* __restrict__ A, const float* __restrict__ W,
    const float* __restrict__ bias, float* __restrict__ C, int K, int ldc)
{
    __shared__ short As[32 * 72];
    __shared__ short Bs[64 * 72];

    const int t   = threadIdx.x;
    const int w   = t >> 6, l = t & 63;
    const int wm  = w >> 1, wn = w & 1;
    const int m0  = blockIdx.x * 32, n0 = blockIdx.y * 64;
    const int arow = t >> 3, ak = (t & 7) * 8;
    const int brow = t >> 2, bk = (t & 3) * 16;
    const int l15 = l & 15, lq = l >> 4;

    const float* ap = &A[(size_t)(m0 + arow) * K + ak];
    const float* bp = &W[(size_t)(n0 + brow) * K + bk];

    floatx4 acc[2] = {};

    float4 a0 = *(const float4*)(ap),      a1 = *(const float4*)(ap + 4);
    float4 b0 = *(const float4*)(bp),      b1 = *(const float4*)(bp + 4);
    float4 b2 = *(const float4*)(bp + 8),  b3 = *(const float4*)(bp + 12);

    for (int k0 = 0; k0 < K; k0 += 64) {
        const int kn = (k0 + 64 < K) ? k0 + 64 : k0;
        float4 na0 = *(const float4*)(ap + kn),      na1 = *(const float4*)(ap + kn + 4);
        float4 nb0 = *(const float4*)(bp + kn),      nb1 = *(const float4*)(bp + kn + 4);
        float4 nb2 = *(const float4*)(bp + kn + 8),  nb3 = *(const float4*)(bp + kn + 12);

        short8 a8  = { f2bf(a0.x), f2bf(a0.y), f2bf(a0.z), f2bf(a0.w),
                       f2bf(a1.x), f2bf(a1.y), f2bf(a1.z), f2bf(a1.w) };
        short8 w80 = { f2bf(b0.x), f2bf(b0.y), f2bf(b0.z), f2bf(b0.w),
                       f2bf(b1.x), f2bf(b1.y), f2bf(b1.z), f2bf(b1.w) };
        short8 w81 = { f2bf(b2.x), f2bf(b2.y), f2bf(b2.z), f2bf(b2.w),
                       f2bf(b3.x), f2bf(b3.y), f2bf(b3.z), f2bf(b3.w) };

        __syncthreads();
        *(short8*)&As[arow * 72 + ak]     = a8;
        *(short8*)&Bs[brow * 72 + bk]     = w80;
        *(short8*)&Bs[brow * 72 + bk + 8] = w81;
        __syncthreads();

        #pragma unroll
        for (int ks = 0; ks < 2; ++ks) {
            short8 af  = *(short8*)&As[(wm * 16 + l15) * 72 + ks * 32 + lq * 8];
            short8 bf0 = *(short8*)&Bs[(wn * 32 +      l15) * 72 + ks * 32 + lq * 8];
            short8 bf1 = *(short8*)&Bs[(wn * 32 + 16 + l15) * 72 + ks * 32 + lq * 8];
            acc[0] = __builtin_amdgcn_mfma_f32_16x16x32_bf16(af, bf0, acc[0], 0, 0, 0);
            acc[1] = __builtin_amdgcn_mfma_f32_16x16x32_bf16(af, bf1, acc[1], 0, 0, 0);
        }

        a0 = na0; a1 = na1; b0 = nb0; b1 = nb1; b2 = nb2; b3 = nb3;
    }

    #pragma unroll
    for (int jj = 0; jj < 2; ++jj) {
        const int col = n0 + wn * 32 + 16 * jj + l15;
        const float bv = bias[col];
        #pragma unroll
        for (int qq = 0; qq < 4; ++qq) {
            const int row = m0 + wm * 16 + lq * 4 + qq;
            C[(size_t)row * ldc + col] = acc[jj][qq] + bv;
        }
    }
}

// ---------------------------------------------------------------------------
extern "C" void kernel_launch(void* const* d_in, const int* in_sizes, int n_in,
                              void* d_out, int out_size, void* d_ws, size_t ws_size,
                              hipStream_t stream) {
    const float* x       = (const float*)d_in[0];
    const int*   seg     = (const int*)  d_in[1];
    const float* att_w   = (const float*)d_in[2];
    const float* w_ih    = (const float*)d_in[3];
    const float* w_hh    = (const float*)d_in[4];
    const float* b_ih    = (const float*)d_in[5];
    const float* b_hh    = (const float*)d_in[6];
    const float* merge_w = (const float*)d_in[7];
    const float* merge_b = (const float*)d_in[8];
    float* out = (float*)d_out;

    float* ws       = (float*)d_ws;
    float* merged   = ws;                              // 4096*1024
    float* center   = merged   + (size_t)NB * 1024;    // 4096*256
    float* neighbor = center   + (size_t)NB * DD;      // 4096*256
    int*   bnd      = (int*)(neighbor + (size_t)NB * DD);  // 4097 ints

    seg_bounds<<<(NN + 255) / 256, 256, 0, stream>>>(seg, bnd);

    seg_kernel<<<NB, 256, 0, stream>>>(x, bnd, att_w, merged, center, neighbor);

    dim3 gg(NB / 64, DD / 16);   // 64 x 16 = 1024 blocks
    gemm_gru<<<gg, 256, 0, stream>>>(center, neighbor, w_ih, w_hh, b_ih, b_hh, merged);

    dim3 g2(NB / 32, DD / 64);   // 128 x 4 = 512 blocks
    gemm_bf16<<<g2, 256, 0, stream>>>(merged, merge_w, merge_b, out, 1024, DD);
}

// Round 13
// 159.780 us; speedup vs baseline: 1.2099x; 1.2099x over previous
//
#include <hip/hip_runtime.h>
#include <math.h>
#include <stdint.h>

#define NN 500000   // nodes
#define NB 4096     // segments
#define DD 256      // feature dim

typedef short  short8  __attribute__((ext_vector_type(8)));
typedef short  short4v __attribute__((ext_vector_type(4)));
typedef float  floatx4 __attribute__((ext_vector_type(4)));
typedef float  f2      __attribute__((ext_vector_type(2)));

__device__ __forceinline__ f2 sp(float v) { return (f2){v, v}; }

// fp32 -> bf16 round-to-nearest-even
__device__ __forceinline__ short f2bf(float f) {
    uint32_t u = __float_as_uint(f);
    u += 0x7fffu + ((u >> 16) & 1u);
    return (short)(u >> 16);
}

// Packed gelu via A&S 7.1.28: erf(z) = 1 - (1+a1 z+..+a6 z^6)^-16, |eps|<=3e-7.
__device__ __forceinline__ f2 gelu2(f2 x) {
    f2 z = __builtin_elementwise_abs(x) * sp(0.70710678118654752440f);
    f2 p = __builtin_elementwise_fma(z, sp(0.0000430638f), sp(0.0002765672f));
    p = __builtin_elementwise_fma(p, z, sp(0.0001520143f));
    p = __builtin_elementwise_fma(p, z, sp(0.0092705272f));
    p = __builtin_elementwise_fma(p, z, sp(0.0422820123f));
    p = __builtin_elementwise_fma(p, z, sp(0.0705230784f));
    p = __builtin_elementwise_fma(p, z, sp(1.0f));
    p = p * p; p = p * p; p = p * p; p = p * p;           // p^16
    f2 r = { __builtin_amdgcn_rcpf(p.x), __builtin_amdgcn_rcpf(p.y) };
    f2 er = __builtin_elementwise_copysign(sp(1.0f) - r, x);
    return sp(0.5f) * x * (sp(1.0f) + er);
}

// ---------------------------------------------------------------------------
// Kernel 0: segment boundary precompute (unchanged).
// ---------------------------------------------------------------------------
__global__ __launch_bounds__(256) void seg_bounds(
    const int* __restrict__ seg, int* __restrict__ bnd)
{
    int i = blockIdx.x * 256 + threadIdx.x;
    if (i >= NN) return;
    int s = seg[i];
    if (i == 0) {
        for (int b = 0; b <= s; ++b) bnd[b] = 0;
    } else {
        int p = seg[i - 1];
        for (int b = p + 1; b <= s; ++b) bnd[b] = i;
    }
    if (i == NN - 1) {
        for (int b = s + 1; b <= NB; ++b) bnd[b] = NN;
    }
}

// ---------------------------------------------------------------------------
// seg kernel v6: COLUMN-SPLIT. Grid (NB, 2): block (b, h2) handles segment b,
// cols [128*h2, 128*h2+128) = heads {2*h2, 2*h2+1}. Softmax denom is per-head
// so the split is communication-free. 4 waves; wave w streams a contiguous
// quarter of the segment's rows; lane l owns cols c0+2l..c0+2l+1 (float2,
// 512B/wave/row coalesced). Per-row serial work ~27 slots (vs 90 full-row).
// 4 rows resident, 2 processed/iter. ~8 blocks/CU -> deep latency hiding.
// ---------------------------------------------------------------------------
__global__ __launch_bounds__(256) void seg_kernel(
    const float* __restrict__ x,
    const int*   __restrict__ bnd,
    const float* __restrict__ att_w,
    float* __restrict__ merged,    // (NB, 1024)
    float* __restrict__ center,    // (NB, 256)
    float* __restrict__ neighbor)  // (NB, 256)
{
    const int b   = blockIdx.x;
    const int h2  = blockIdx.y;          // column-half 0/1
    const int c0  = h2 * 128;            // first col of this block
    const int tid = threadIdx.x;
    const int w   = tid >> 6;
    const int l   = tid & 63;

    const int start = bnd[b];
    const int end   = bnd[b + 1];

    const int cnt = end - start;
    const int q = cnt >> 2, r = cnt & 3;
    const int my_start = start + w * q + (w < r ? w : r);
    const int my_cnt   = q + (w < r ? 1 : 0);

    const f2 aw = *reinterpret_cast<const f2*>(&att_w[c0 + 2 * l]);

    f2 cS = sp(0.f);                 // segsum(gelu)
    f2 sS = sp(0.f);                 // segsum(x)
    f2 mS = sp(-INFINITY);           // segmax(x)
    f2 aS = sp(0.f);                 // sum e*x
    float lsum = 0.f;                // sum e (this wave, this lane's head)

    auto process = [&](const f2& v) {
        f2 g = gelu2(v);
        cS += g;
        sS += v;
        mS = __builtin_elementwise_max(mS, v);
        f2 tp = v * aw;
        float t = tp.x + tp.y;
        // reduce over the 32 lanes holding this head's 64 cols
        t += __shfl_xor(t, 1, 64);
        t += __shfl_xor(t, 2, 64);
        t += __shfl_xor(t, 4, 64);
        t += __shfl_xor(t, 8, 64);
        t += __shfl_xor(t, 16, 64);
        float alpha = fmaxf(t, 0.2f * t);   // leaky_relu(0.2)
        float e = __expf(alpha);            // no max-shift: |alpha| small
        lsum += e;
        aS = __builtin_elementwise_fma(sp(e), v, aS);
    };

    const float* __restrict__ xl = x + c0 + 2 * l;
    auto LD = [&](int row) -> f2 {
        int rc = row < (NN - 1) ? row : (NN - 1);   // clamp: over-reads discarded
        return *reinterpret_cast<const f2*>(&xl[(size_t)rc * DD]);
    };

    // 4 rows resident, 2 processed per iteration
    f2 q0 = LD(my_start),     q1 = LD(my_start + 1),
       q2 = LD(my_start + 2), q3 = LD(my_start + 3);
    int ip = my_start + 4;
    int rem = my_cnt;
    while (rem >= 2) {
        f2 f0 = LD(ip), f1 = LD(ip + 1);
        process(q0); process(q1);
        q0 = q2; q1 = q3; q2 = f0; q3 = f1;
        ip += 2; rem -= 2;
    }
    if (rem) process(q0);

    // ---- cross-wave combine (c, s, m, a over 128 cols = 8 KB) ----
    __shared__ float lds[4][4][128];
    __shared__ float ldsl[4][2];         // per-wave, per-local-head denom
    const int c = 2 * l;
    lds[0][w][c] = cS.x; lds[0][w][c+1] = cS.y;
    lds[1][w][c] = sS.x; lds[1][w][c+1] = sS.y;
    lds[2][w][c] = mS.x; lds[2][w][c+1] = mS.y;
    lds[3][w][c] = aS.x; lds[3][w][c+1] = aS.y;
    if ((l & 31) == 0) ldsl[w][l >> 5] = lsum;
    __syncthreads();

    if (tid < 128) {
        const int d = tid;               // local col 0..127
        float cs = lds[0][0][d] + lds[0][1][d] + lds[0][2][d] + lds[0][3][d];
        float ss = lds[1][0][d] + lds[1][1][d] + lds[1][2][d] + lds[1][3][d];
        float mm = fmaxf(fmaxf(lds[2][0][d], lds[2][1][d]),
                         fmaxf(lds[2][2][d], lds[2][3][d]));
        float ac = lds[3][0][d] + lds[3][1][d] + lds[3][2][d] + lds[3][3][d];
        const int hl = d >> 6;           // local head 0/1
        float denom = ldsl[0][hl] + ldsl[1][hl] + ldsl[2][hl] + ldsl[3][hl];
        float att = (denom > 0.f) ? ac / denom : 0.f;
        float nm = gelu2((f2){mm, mm}).x;   // neighbor = gelu(segmax(x))

        const int gcol = c0 + d;         // global col
        float* mrow = merged + (size_t)b * 1024;
        mrow[256 + gcol] = att;
        mrow[512 + gcol] = mm;
        mrow[768 + gcol] = ss;
        center  [(size_t)b * DD + gcol] = cs;
        neighbor[(size_t)b * DD + gcol] = nm;
    }
}

// ---------------------------------------------------------------------------
// Fused GRU GEMM v3 (unchanged from round 11)
// ---------------------------------------------------------------------------
__global__ __launch_bounds__(256) void gemm_gru(
    const float* __restrict__ center,    // (NB, 256)
    const float* __restrict__ neighbor,  // (NB, 256)
    const float* __restrict__ w_ih,      // (768, 256)
    const float* __restrict__ w_hh,      // (768, 256)
    const float* __restrict__ b_ih,      // (768)
    const float* __restrict__ b_hh,      // (768)
    float* __restrict__ merged)          // (NB, 1024)
{
    __shared__ short Ac[64 * 40];
    __shared__ short An[64 * 40];
    __shared__ short Wt[6][16 * 40];

    const int t   = threadIdx.x;
    const int w   = t >> 6, l = t & 63;
    const int m0  = blockIdx.x * 64;
    const int j0  = blockIdx.y * 16;
    const int lr  = t >> 2;
    const int lc  = (t & 3) * 8;
    const int l15 = l & 15, lq = l >> 4;

    int wg[3], wrow[3], wk4[3];
    const float* wbase[3];
    #pragma unroll
    for (int i = 0; i < 3; ++i) {
        int f = i * 256 + t;
        wg[i] = f >> 7;
        int rem2 = f & 127;
        wrow[i] = rem2 >> 3;
        wk4[i]  = rem2 & 7;
        wbase[i] = (wg[i] < 3)
            ? &w_ih[(size_t)(wg[i] * 256 + j0 + wrow[i]) * 256 + wk4[i] * 4]
            : &w_hh[(size_t)((wg[i] - 3) * 256 + j0 + wrow[i]) * 256 + wk4[i] * 4];
    }
    const float* crp = &center  [(size_t)(m0 + lr) * 256 + lc];
    const float* nrp = &neighbor[(size_t)(m0 + lr) * 256 + lc];

    floatx4 acc[6] = {};

    float4 c0 = *(const float4*)(crp),     c1 = *(const float4*)(crp + 4);
    float4 e0 = *(const float4*)(nrp),     e1 = *(const float4*)(nrp + 4);
    float4 v0 = *(const float4*)(wbase[0]);
    float4 v1 = *(const float4*)(wbase[1]);
    float4 v2 = *(const float4*)(wbase[2]);

    for (int k0 = 0; k0 < 256; k0 += 32) {
        const int kn = (k0 + 32 < 256) ? k0 + 32 : k0;
        float4 nc0 = *(const float4*)(crp + kn), nc1 = *(const float4*)(crp + kn + 4);
        float4 ne0 = *(const float4*)(nrp + kn), ne1 = *(const float4*)(nrp + kn + 4);
        float4 nv0 = *(const float4*)(wbase[0] + kn);
        float4 nv1 = *(const float4*)(wbase[1] + kn);
        float4 nv2 = *(const float4*)(wbase[2] + kn);

        short8 a8 = { f2bf(c0.x), f2bf(c0.y), f2bf(c0.z), f2bf(c0.w),
                      f2bf(c1.x), f2bf(c1.y), f2bf(c1.z), f2bf(c1.w) };
        short8 n8 = { f2bf(e0.x), f2bf(e0.y), f2bf(e0.z), f2bf(e0.w),
                      f2bf(e1.x), f2bf(e1.y), f2bf(e1.z), f2bf(e1.w) };
        short4v w40 = { f2bf(v0.x), f2bf(v0.y), f2bf(v0.z), f2bf(v0.w) };
        short4v w41 = { f2bf(v1.x), f2bf(v1.y), f2bf(v1.z), f2bf(v1.w) };
        short4v w42 = { f2bf(v2.x), f2bf(v2.y), f2bf(v2.z), f2bf(v2.w) };

        __syncthreads();
        *(short8*)&Ac[lr * 40 + lc] = a8;
        *(short8*)&An[lr * 40 + lc] = n8;
        *(short4v*)&Wt[wg[0]][wrow[0] * 40 + wk4[0] * 4] = w40;
        *(short4v*)&Wt[wg[1]][wrow[1] * 40 + wk4[1] * 4] = w41;
        *(short4v*)&Wt[wg[2]][wrow[2] * 40 + wk4[2] * 4] = w42;
        __syncthreads();

        short8 afc = *(short8*)&Ac[(w * 16 + l15) * 40 + lq * 8];
        short8 afn = *(short8*)&An[(w * 16 + l15) * 40 + lq * 8];
        #pragma unroll
        for (int gg = 0; gg < 6; ++gg) {
            short8 bf = *(short8*)&Wt[gg][l15 * 40 + lq * 8];
            acc[gg] = __builtin_amdgcn_mfma_f32_16x16x32_bf16(
                (gg < 3) ? afc : afn, bf, acc[gg], 0, 0, 0);
        }

        c0 = nc0; c1 = nc1; e0 = ne0; e1 = ne1;
        v0 = nv0; v1 = nv1; v2 = nv2;
    }

    const int col = j0 + l15;
    const float bir = b_ih[col], biz = b_ih[256 + col], bin = b_ih[512 + col];
    const float bhr = b_hh[col], bhz = b_hh[256 + col], bhn = b_hh[512 + col];
    #pragma unroll
    for (int qq = 0; qq < 4; ++qq) {
        const int row = m0 + w * 16 + lq * 4 + qq;
        float rr = 1.f / (1.f + __expf(-(acc[0][qq] + bir + acc[3][qq] + bhr)));
        float zz = 1.f / (1.f + __expf(-(acc[1][qq] + biz + acc[4][qq] + bhz)));
        float ng = tanhf(acc[2][qq] + bin + rr * (acc[5][qq] + bhn));
        float nb = neighbor[(size_t)row * 256 + col];
        merged[(size_t)row * 1024 + col] = (1.f - zz) * ng + zz * nb;
    }
}

// ---------------------------------------------------------------------------
// bf16 MFMA GEMM v3 (merge, unchanged from round 11)
// ---------------------------------------------------------------------------
__global__ __launch_bounds__(256) void gemm_bf16(
    const float* __restrict__ A, const float* __restrict__ W,
    const float* __restrict__ bias, float* __restrict__ C, int K, int ldc)
{
    __shared__ short As[32 * 72];
    __shared__ short Bs[64 * 72];

    const int t   = threadIdx.x;
    const int w   = t >> 6, l = t & 63;
    const int wm  = w >> 1, wn = w & 1;
    const int m0  = blockIdx.x * 32, n0 = blockIdx.y * 64;
    const int arow = t >> 3, ak = (t & 7) * 8;
    const int brow = t >> 2, bk = (t & 3) * 16;
    const int l15 = l & 15, lq = l >> 4;

    const float* ap = &A[(size_t)(m0 + arow) * K + ak];
    const float* bp = &W[(size_t)(n0 + brow) * K + bk];

    floatx4 acc[2] = {};

    float4 a0 = *(const float4*)(ap),      a1 = *(const float4*)(ap + 4);
    float4 b0 = *(const float4*)(bp),      b1 = *(const float4*)(bp + 4);
    float4 b2 = *(const float4*)(bp + 8),  b3 = *(const float4*)(bp + 12);

    for (int k0 = 0; k0 < K; k0 += 64) {
        const int kn = (k0 + 64 < K) ? k0 + 64 : k0;
        float4 na0 = *(const float4*)(ap + kn),      na1 = *(const float4*)(ap + kn + 4);
        float4 nb0 = *(const float4*)(bp + kn),      nb1 = *(const float4*)(bp + kn + 4);
        float4 nb2 = *(const float4*)(bp + kn + 8),  nb3 = *(const float4*)(bp + kn + 12);

        short8 a8  = { f2bf(a0.x), f2bf(a0.y), f2bf(a0.z), f2bf(a0.w),
                       f2bf(a1.x), f2bf(a1.y), f2bf(a1.z), f2bf(a1.w) };
        short8 w80 = { f2bf(b0.x), f2bf(b0.y), f2bf(b0.z), f2bf(b0.w),
                       f2bf(b1.x), f2bf(b1.y), f2bf(b1.z), f2bf(b1.w) };
        short8 w81 = { f2bf(b2.x), f2bf(b2.y), f2bf(b2.z), f2bf(b2.w),
                       f2bf(b3.x), f2bf(b3.y), f2bf(b3.z), f2bf(b3.w) };

        __syncthreads();
        *(short8*)&As[arow * 72 + ak]     = a8;
        *(short8*)&Bs[brow * 72 + bk]     = w80;
        *(short8*)&Bs[brow * 72 + bk + 8] = w81;
        __syncthreads();

        #pragma unroll
        for (int ks = 0; ks < 2; ++ks) {
            short8 af  = *(short8*)&As[(wm * 16 + l15) * 72 + ks * 32 + lq * 8];
            short8 bf0 = *(short8*)&Bs[(wn * 32 +      l15) * 72 + ks * 32 + lq * 8];
            short8 bf1 = *(short8*)&Bs[(wn * 32 + 16 + l15) * 72 + ks * 32 + lq * 8];
            acc[0] = __builtin_amdgcn_mfma_f32_16x16x32_bf16(af, bf0, acc[0], 0, 0, 0);
            acc[1] = __builtin_amdgcn_mfma_f32_16x16x32_bf16(af, bf1, acc[1], 0, 0, 0);
        }

        a0 = na0; a1 = na1; b0 = nb0; b1 = nb1; b2 = nb2; b3 = nb3;
    }

    #pragma unroll
    for (int jj = 0; jj < 2; ++jj) {
        const int col = n0 + wn * 32 + 16 * jj + l15;
        const float bv = bias[col];
        #pragma unroll
        for (int qq = 0; qq < 4; ++qq) {
            const int row = m0 + wm * 16 + lq * 4 + qq;
            C[(size_t)row * ldc + col] = acc[jj][qq] + bv;
        }
    }
}

// ---------------------------------------------------------------------------
extern "C" void kernel_launch(void* const* d_in, const int* in_sizes, int n_in,
                              void* d_out, int out_size, void* d_ws, size_t ws_size,
                              hipStream_t stream) {
    const float* x       = (const float*)d_in[0];
    const int*   seg     = (const int*)  d_in[1];
    const float* att_w   = (const float*)d_in[2];
    const float* w_ih    = (const float*)d_in[3];
    const float* w_hh    = (const float*)d_in[4];
    const float* b_ih    = (const float*)d_in[5];
    const float* b_hh    = (const float*)d_in[6];
    const float* merge_w = (const float*)d_in[7];
    const float* merge_b = (const float*)d_in[8];
    float* out = (float*)d_out;

    float* ws       = (float*)d_ws;
    float* merged   = ws;                              // 4096*1024
    float* center   = merged   + (size_t)NB * 1024;    // 4096*256
    float* neighbor = center   + (size_t)NB * DD;      // 4096*256
    int*   bnd      = (int*)(neighbor + (size_t)NB * DD);  // 4097 ints

    seg_bounds<<<(NN + 255) / 256, 256, 0, stream>>>(seg, bnd);

    dim3 gs(NB, 2);   // column-split: 8192 blocks
    seg_kernel<<<gs, 256, 0, stream>>>(x, bnd, att_w, merged, center, neighbor);

    dim3 gg(NB / 64, DD / 16);   // 64 x 16 = 1024 blocks
    gemm_gru<<<gg, 256, 0, stream>>>(center, neighbor, w_ih, w_hh, b_ih, b_hh, merged);

    dim3 g2(NB / 32, DD / 64);   // 128 x 4 = 512 blocks
    gemm_bf16<<<g2, 256, 0, stream>>>(merged, merge_w, merge_b, out, 1024, DD);
}

// Round 14
// 141.415 us; speedup vs baseline: 1.3670x; 1.1299x over previous
//
#include <hip/hip_runtime.h>
#include <math.h>
#include <stdint.h>

#define NN 500000   // nodes
#define NB 4096     // segments
#define DD 256      // feature dim

typedef short  short8  __attribute__((ext_vector_type(8)));
typedef short  short4v __attribute__((ext_vector_type(4)));
typedef float  floatx4 __attribute__((ext_vector_type(4)));
typedef float  f2      __attribute__((ext_vector_type(2)));

__device__ __forceinline__ f2 sp(float v) { return (f2){v, v}; }

// fp32 -> bf16 round-to-nearest-even
__device__ __forceinline__ short f2bf(float f) {
    uint32_t u = __float_as_uint(f);
    u += 0x7fffu + ((u >> 16) & 1u);
    return (short)(u >> 16);
}
// bf16 -> fp32
__device__ __forceinline__ float bf2f(short s) {
    uint32_t u = ((uint32_t)(unsigned short)s) << 16;
    return __uint_as_float(u);
}

// Packed gelu via A&S 7.1.28: erf(z) = 1 - (1+a1 z+..+a6 z^6)^-16, |eps|<=3e-7.
__device__ __forceinline__ f2 gelu2(f2 x) {
    f2 z = __builtin_elementwise_abs(x) * sp(0.70710678118654752440f);
    f2 p = __builtin_elementwise_fma(z, sp(0.0000430638f), sp(0.0002765672f));
    p = __builtin_elementwise_fma(p, z, sp(0.0001520143f));
    p = __builtin_elementwise_fma(p, z, sp(0.0092705272f));
    p = __builtin_elementwise_fma(p, z, sp(0.0422820123f));
    p = __builtin_elementwise_fma(p, z, sp(0.0705230784f));
    p = __builtin_elementwise_fma(p, z, sp(1.0f));
    p = p * p; p = p * p; p = p * p; p = p * p;           // p^16
    f2 r = { __builtin_amdgcn_rcpf(p.x), __builtin_amdgcn_rcpf(p.y) };
    f2 er = __builtin_elementwise_copysign(sp(1.0f) - r, x);
    return sp(0.5f) * x * (sp(1.0f) + er);
}

// ---------------------------------------------------------------------------
// Kernel 0: segment boundary precompute (unchanged).
// ---------------------------------------------------------------------------
__global__ __launch_bounds__(256) void seg_bounds(
    const int* __restrict__ seg, int* __restrict__ bnd)
{
    int i = blockIdx.x * 256 + threadIdx.x;
    if (i >= NN) return;
    int s = seg[i];
    if (i == 0) {
        for (int b = 0; b <= s; ++b) bnd[b] = 0;
    } else {
        int p = seg[i - 1];
        for (int b = p + 1; b <= s; ++b) bnd[b] = i;
    }
    if (i == NN - 1) {
        for (int b = s + 1; b <= NB; ++b) bnd[b] = NN;
    }
}

// ---------------------------------------------------------------------------
// seg kernel v7 = round-11 v4 structure (the 150.8 config), but outputs bf16:
// merged_bf slices (att/max/sum), center_bf, neighbor_bf. Same fp32 math;
// quantization moved from GEMM staging to producer (numerically identical).
// ---------------------------------------------------------------------------
__global__ __launch_bounds__(256, 8) void seg_kernel(
    const float* __restrict__ x,
    const int*   __restrict__ bnd,
    const float* __restrict__ att_w,
    short* __restrict__ merged_bf,   // (NB, 1024) bf16
    short* __restrict__ center_bf,   // (NB, 256)  bf16
    short* __restrict__ neighbor_bf) // (NB, 256)  bf16
{
    const int b   = blockIdx.x;
    const int tid = threadIdx.x;
    const int w   = tid >> 6;
    const int l   = tid & 63;

    const int start = bnd[b];
    const int end   = bnd[b + 1];

    const int cnt = end - start;
    const int q = cnt >> 2, r = cnt & 3;
    const int my_start = start + w * q + (w < r ? w : r);
    const int my_cnt   = q + (w < r ? 1 : 0);

    const float4 awv = *reinterpret_cast<const float4*>(&att_w[4 * l]);
    const f2 aw01 = {awv.x, awv.y}, aw23 = {awv.z, awv.w};

    f2 c01 = sp(0.f), c23 = sp(0.f);                 // segsum(gelu)
    f2 s01 = sp(0.f), s23 = sp(0.f);                 // segsum(x)
    f2 m01 = sp(-INFINITY), m23 = sp(-INFINITY);     // segmax(x)
    f2 a01 = sp(0.f), a23 = sp(0.f);                 // sum e*x
    float lsum = 0.f;                                 // sum e (per head)

    auto process = [&](const float4& v) {
        f2 vl = {v.x, v.y}, vh = {v.z, v.w};
        f2 gl = gelu2(vl), gh = gelu2(vh);
        c01 += gl; c23 += gh;
        s01 += vl; s23 += vh;
        m01 = __builtin_elementwise_max(m01, vl);
        m23 = __builtin_elementwise_max(m23, vh);
        f2 tp = __builtin_elementwise_fma(vh, aw23, vl * aw01);
        float t = tp.x + tp.y;
        t += __shfl_xor(t, 1, 64);
        t += __shfl_xor(t, 2, 64);
        t += __shfl_xor(t, 4, 64);
        t += __shfl_xor(t, 8, 64);
        float alpha = fmaxf(t, 0.2f * t);   // leaky_relu(0.2)
        float e = __expf(alpha);            // no max-shift: |alpha| small
        lsum += e;
        f2 ev = sp(e);
        a01 = __builtin_elementwise_fma(ev, vl, a01);
        a23 = __builtin_elementwise_fma(ev, vh, a23);
    };

    const float* __restrict__ xl = x + 4 * l;
    auto LD = [&](int row) -> float4 {
        int rc = row < (NN - 1) ? row : (NN - 1);   // clamp: over-reads discarded
        return *reinterpret_cast<const float4*>(&xl[(size_t)rc * DD]);
    };

    float4 q0 = LD(my_start),     q1 = LD(my_start + 1),
           q2 = LD(my_start + 2), q3 = LD(my_start + 3);
    int ip = my_start + 4;
    int rem = my_cnt;
    while (rem >= 2) {
        float4 f0 = LD(ip), f1 = LD(ip + 1);
        process(q0); process(q1);
        q0 = q2; q1 = q3; q2 = f0; q3 = f1;
        ip += 2; rem -= 2;
    }
    if (rem) process(q0);

    __shared__ float lds[4][4][256];
    __shared__ float ldsl[4][4];
    const int c = 4 * l;
    lds[0][w][c+0] = c01.x; lds[0][w][c+1] = c01.y; lds[0][w][c+2] = c23.x; lds[0][w][c+3] = c23.y;
    lds[1][w][c+0] = s01.x; lds[1][w][c+1] = s01.y; lds[1][w][c+2] = s23.x; lds[1][w][c+3] = s23.y;
    lds[2][w][c+0] = m01.x; lds[2][w][c+1] = m01.y; lds[2][w][c+2] = m23.x; lds[2][w][c+3] = m23.y;
    lds[3][w][c+0] = a01.x; lds[3][w][c+1] = a01.y; lds[3][w][c+2] = a23.x; lds[3][w][c+3] = a23.y;
    if ((l & 15) == 0) ldsl[w][l >> 4] = lsum;
    __syncthreads();

    const int d = tid;   // output column
    float cs = lds[0][0][d] + lds[0][1][d] + lds[0][2][d] + lds[0][3][d];
    float ss = lds[1][0][d] + lds[1][1][d] + lds[1][2][d] + lds[1][3][d];
    float mm = fmaxf(fmaxf(lds[2][0][d], lds[2][1][d]), fmaxf(lds[2][2][d], lds[2][3][d]));
    float ac = lds[3][0][d] + lds[3][1][d] + lds[3][2][d] + lds[3][3][d];
    const int h = d >> 6;
    float denom = ldsl[0][h] + ldsl[1][h] + ldsl[2][h] + ldsl[3][h];
    float att = (denom > 0.f) ? ac / denom : 0.f;
    float nm = gelu2((f2){mm, mm}).x;   // neighbor = gelu(segmax(x))

    short* mrow = merged_bf + (size_t)b * 1024;
    mrow[256 + d] = f2bf(att);
    mrow[512 + d] = f2bf(mm);
    mrow[768 + d] = f2bf(ss);
    center_bf  [(size_t)b * DD + d] = f2bf(cs);
    neighbor_bf[(size_t)b * DD + d] = f2bf(nm);
}

// ---------------------------------------------------------------------------
// Fused GRU GEMM v4: A-operands already bf16 -> staging = 1 short8/thread per
// operand, zero conversion. W fp32->bf16 (small, cached). Register dbuf kept.
// Writes rnn slice of merged_bf (bf16).
// ---------------------------------------------------------------------------
__global__ __launch_bounds__(256) void gemm_gru(
    const short* __restrict__ center_bf,    // (NB, 256) bf16
    const short* __restrict__ neighbor_bf,  // (NB, 256) bf16
    const float* __restrict__ w_ih,         // (768, 256)
    const float* __restrict__ w_hh,         // (768, 256)
    const float* __restrict__ b_ih,         // (768)
    const float* __restrict__ b_hh,         // (768)
    short* __restrict__ merged_bf)          // (NB, 1024) bf16
{
    __shared__ short Ac[64 * 40];
    __shared__ short An[64 * 40];
    __shared__ short Wt[6][16 * 40];

    const int t   = threadIdx.x;
    const int w   = t >> 6, l = t & 63;
    const int m0  = blockIdx.x * 64;
    const int j0  = blockIdx.y * 16;
    const int lr  = t >> 2;
    const int lc  = (t & 3) * 8;
    const int l15 = l & 15, lq = l >> 4;

    int wg[3], wrow[3], wk4[3];
    const float* wbase[3];
    #pragma unroll
    for (int i = 0; i < 3; ++i) {
        int f = i * 256 + t;
        wg[i] = f >> 7;
        int rem2 = f & 127;
        wrow[i] = rem2 >> 3;
        wk4[i]  = rem2 & 7;
        wbase[i] = (wg[i] < 3)
            ? &w_ih[(size_t)(wg[i] * 256 + j0 + wrow[i]) * 256 + wk4[i] * 4]
            : &w_hh[(size_t)((wg[i] - 3) * 256 + j0 + wrow[i]) * 256 + wk4[i] * 4];
    }
    const short* crp = &center_bf  [(size_t)(m0 + lr) * 256 + lc];
    const short* nrp = &neighbor_bf[(size_t)(m0 + lr) * 256 + lc];

    floatx4 acc[6] = {};

    short8 c8 = *(const short8*)(crp);
    short8 n8 = *(const short8*)(nrp);
    float4 v0 = *(const float4*)(wbase[0]);
    float4 v1 = *(const float4*)(wbase[1]);
    float4 v2 = *(const float4*)(wbase[2]);

    for (int k0 = 0; k0 < 256; k0 += 32) {
        const int kn = (k0 + 32 < 256) ? k0 + 32 : k0;
        short8 nc8 = *(const short8*)(crp + kn);
        short8 nn8 = *(const short8*)(nrp + kn);
        float4 nv0 = *(const float4*)(wbase[0] + kn);
        float4 nv1 = *(const float4*)(wbase[1] + kn);
        float4 nv2 = *(const float4*)(wbase[2] + kn);

        short4v w40 = { f2bf(v0.x), f2bf(v0.y), f2bf(v0.z), f2bf(v0.w) };
        short4v w41 = { f2bf(v1.x), f2bf(v1.y), f2bf(v1.z), f2bf(v1.w) };
        short4v w42 = { f2bf(v2.x), f2bf(v2.y), f2bf(v2.z), f2bf(v2.w) };

        __syncthreads();
        *(short8*)&Ac[lr * 40 + lc] = c8;
        *(short8*)&An[lr * 40 + lc] = n8;
        *(short4v*)&Wt[wg[0]][wrow[0] * 40 + wk4[0] * 4] = w40;
        *(short4v*)&Wt[wg[1]][wrow[1] * 40 + wk4[1] * 4] = w41;
        *(short4v*)&Wt[wg[2]][wrow[2] * 40 + wk4[2] * 4] = w42;
        __syncthreads();

        short8 afc = *(short8*)&Ac[(w * 16 + l15) * 40 + lq * 8];
        short8 afn = *(short8*)&An[(w * 16 + l15) * 40 + lq * 8];
        #pragma unroll
        for (int gg = 0; gg < 6; ++gg) {
            short8 bf = *(short8*)&Wt[gg][l15 * 40 + lq * 8];
            acc[gg] = __builtin_amdgcn_mfma_f32_16x16x32_bf16(
                (gg < 3) ? afc : afn, bf, acc[gg], 0, 0, 0);
        }

        c8 = nc8; n8 = nn8;
        v0 = nv0; v1 = nv1; v2 = nv2;
    }

    const int col = j0 + l15;
    const float bir = b_ih[col], biz = b_ih[256 + col], bin = b_ih[512 + col];
    const float bhr = b_hh[col], bhz = b_hh[256 + col], bhn = b_hh[512 + col];
    #pragma unroll
    for (int qq = 0; qq < 4; ++qq) {
        const int row = m0 + w * 16 + lq * 4 + qq;
        float rr = 1.f / (1.f + __expf(-(acc[0][qq] + bir + acc[3][qq] + bhr)));
        float zz = 1.f / (1.f + __expf(-(acc[1][qq] + biz + acc[4][qq] + bhz)));
        float ng = tanhf(acc[2][qq] + bin + rr * (acc[5][qq] + bhn));
        float nb = bf2f(neighbor_bf[(size_t)row * 256 + col]);
        merged_bf[(size_t)row * 1024 + col] = f2bf((1.f - zz) * ng + zz * nb);
    }
}

// ---------------------------------------------------------------------------
// bf16 MFMA GEMM v4 (merge): A is native bf16 (merged_bf) -> staging =
// 1 short8/thread, no conversion. 32x64 tile, BK=64, register dbuf.
// ---------------------------------------------------------------------------
__global__ __launch_bounds__(256) void gemm_bf16(
    const short* __restrict__ A,          // (NB, 1024) bf16
    const float* __restrict__ W,          // (256, 1024)
    const float* __restrict__ bias,       // (256)
    float* __restrict__ C, int K, int ldc)
{
    __shared__ short As[32 * 72];
    __shared__ short Bs[64 * 72];

    const int t   = threadIdx.x;
    const int w   = t >> 6, l = t & 63;
    const int wm  = w >> 1, wn = w & 1;
    const int m0  = blockIdx.x * 32, n0 = blockIdx.y * 64;
    const int arow = t >> 3, ak = (t & 7) * 8;    // A: 8 shorts/thread
    const int brow = t >> 2, bk = (t & 3) * 16;   // B: 16 floats/thread
    const int l15 = l & 15, lq = l >> 4;

    const short* ap = &A[(size_t)(m0 + arow) * K + ak];
    const float* bp = &W[(size_t)(n0 + brow) * K + bk];

    floatx4 acc[2] = {};

    short8 a8 = *(const short8*)(ap);
    float4 b0 = *(const float4*)(bp),      b1 = *(const float4*)(bp + 4);
    float4 b2 = *(const float4*)(bp + 8),  b3 = *(const float4*)(bp + 12);

    for (int k0 = 0; k0 < K; k0 += 64) {
        const int kn = (k0 + 64 < K) ? k0 + 64 : k0;
        short8 na8 = *(const short8*)(ap + kn);
        float4 nb0 = *(const float4*)(bp + kn),      nb1 = *(const float4*)(bp + kn + 4);
        float4 nb2 = *(const float4*)(bp + kn + 8),  nb3 = *(const float4*)(bp + kn + 12);

        short8 w80 = { f2bf(b0.x), f2bf(b0.y), f2bf(b0.z), f2bf(b0.w),
                       f2bf(b1.x), f2bf(b1.y), f2bf(b1.z), f2bf(b1.w) };
        short8 w81 = { f2bf(b2.x), f2bf(b2.y), f2bf(b2.z), f2bf(b2.w),
                       f2bf(b3.x), f2bf(b3.y), f2bf(b3.z), f2bf(b3.w) };

        __syncthreads();
        *(short8*)&As[arow * 72 + ak]     = a8;
        *(short8*)&Bs[brow * 72 + bk]     = w80;
        *(short8*)&Bs[brow * 72 + bk + 8] = w81;
        __syncthreads();

        #pragma unroll
        for (int ks = 0; ks < 2; ++ks) {
            short8 af  = *(short8*)&As[(wm * 16 + l15) * 72 + ks * 32 + lq * 8];
            short8 bf0 = *(short8*)&Bs[(wn * 32 +      l15) * 72 + ks * 32 + lq * 8];
            short8 bf1 = *(short8*)&Bs[(wn * 32 + 16 + l15) * 72 + ks * 32 + lq * 8];
            acc[0] = __builtin_amdgcn_mfma_f32_16x16x32_bf16(af, bf0, acc[0], 0, 0, 0);
            acc[1] = __builtin_amdgcn_mfma_f32_16x16x32_bf16(af, bf1, acc[1], 0, 0, 0);
        }

        a8 = na8; b0 = nb0; b1 = nb1; b2 = nb2; b3 = nb3;
    }

    #pragma unroll
    for (int jj = 0; jj < 2; ++jj) {
        const int col = n0 + wn * 32 + 16 * jj + l15;
        const float bv = bias[col];
        #pragma unroll
        for (int qq = 0; qq < 4; ++qq) {
            const int row = m0 + wm * 16 + lq * 4 + qq;
            C[(size_t)row * ldc + col] = acc[jj][qq] + bv;
        }
    }
}

// ---------------------------------------------------------------------------
extern "C" void kernel_launch(void* const* d_in, const int* in_sizes, int n_in,
                              void* d_out, int out_size, void* d_ws, size_t ws_size,
                              hipStream_t stream) {
    const float* x       = (const float*)d_in[0];
    const int*   seg     = (const int*)  d_in[1];
    const float* att_w   = (const float*)d_in[2];
    const float* w_ih    = (const float*)d_in[3];
    const float* w_hh    = (const float*)d_in[4];
    const float* b_ih    = (const float*)d_in[5];
    const float* b_hh    = (const float*)d_in[6];
    const float* merge_w = (const float*)d_in[7];
    const float* merge_b = (const float*)d_in[8];
    float* out = (float*)d_out;

    // ws layout (bf16 pipeline):
    short* merged_bf   = (short*)d_ws;                       // NB*1024 shorts (8 MB)
    short* center_bf   = merged_bf   + (size_t)NB * 1024;    // NB*256 shorts (2 MB)
    short* neighbor_bf = center_bf   + (size_t)NB * DD;      // NB*256 shorts (2 MB)
    int*   bnd         = (int*)(neighbor_bf + (size_t)NB * DD);  // 4097 ints

    seg_bounds<<<(NN + 255) / 256, 256, 0, stream>>>(seg, bnd);

    seg_kernel<<<NB, 256, 0, stream>>>(x, bnd, att_w, merged_bf, center_bf, neighbor_bf);

    dim3 gg(NB / 64, DD / 16);   // 64 x 16 = 1024 blocks
    gemm_gru<<<gg, 256, 0, stream>>>(center_bf, neighbor_bf, w_ih, w_hh, b_ih, b_hh, merged_bf);

    dim3 g2(NB / 32, DD / 64);   // 128 x 4 = 512 blocks
    gemm_bf16<<<g2, 256, 0, stream>>>(merged_bf, merge_w, merge_b, out, 1024, DD);
}

// Round 15
// 140.237 us; speedup vs baseline: 1.3785x; 1.0084x over previous
//
#include <hip/hip_runtime.h>
#include <math.h>
#include <stdint.h>

#define NN 500000   // nodes
#define NB 4096     // segments
#define DD 256      // feature dim

typedef short  short8  __attribute__((ext_vector_type(8)));
typedef short  short4v __attribute__((ext_vector_type(4)));
typedef float  floatx4 __attribute__((ext_vector_type(4)));
typedef float  f2      __attribute__((ext_vector_type(2)));

__device__ __forceinline__ f2 sp(float v) { return (f2){v, v}; }

// fp32 -> bf16 round-to-nearest-even
__device__ __forceinline__ short f2bf(float f) {
    uint32_t u = __float_as_uint(f);
    u += 0x7fffu + ((u >> 16) & 1u);
    return (short)(u >> 16);
}
// bf16 -> fp32
__device__ __forceinline__ float bf2f(short s) {
    uint32_t u = ((uint32_t)(unsigned short)s) << 16;
    return __uint_as_float(u);
}

// Packed gelu via A&S 7.1.28: erf(z) = 1 - (1+a1 z+..+a6 z^6)^-16, |eps|<=3e-7.
__device__ __forceinline__ f2 gelu2(f2 x) {
    f2 z = __builtin_elementwise_abs(x) * sp(0.70710678118654752440f);
    f2 p = __builtin_elementwise_fma(z, sp(0.0000430638f), sp(0.0002765672f));
    p = __builtin_elementwise_fma(p, z, sp(0.0001520143f));
    p = __builtin_elementwise_fma(p, z, sp(0.0092705272f));
    p = __builtin_elementwise_fma(p, z, sp(0.0422820123f));
    p = __builtin_elementwise_fma(p, z, sp(0.0705230784f));
    p = __builtin_elementwise_fma(p, z, sp(1.0f));
    p = p * p; p = p * p; p = p * p; p = p * p;           // p^16
    f2 r = { __builtin_amdgcn_rcpf(p.x), __builtin_amdgcn_rcpf(p.y) };
    f2 er = __builtin_elementwise_copysign(sp(1.0f) - r, x);
    return sp(0.5f) * x * (sp(1.0f) + er);
}

// ---------------------------------------------------------------------------
// Kernel 0: segment boundary precompute (unchanged).
// ---------------------------------------------------------------------------
__global__ __launch_bounds__(256) void seg_bounds(
    const int* __restrict__ seg, int* __restrict__ bnd)
{
    int i = blockIdx.x * 256 + threadIdx.x;
    if (i >= NN) return;
    int s = seg[i];
    if (i == 0) {
        for (int b = 0; b <= s; ++b) bnd[b] = 0;
    } else {
        int p = seg[i - 1];
        for (int b = p + 1; b <= s; ++b) bnd[b] = i;
    }
    if (i == NN - 1) {
        for (int b = s + 1; b <= NB; ++b) bnd[b] = NN;
    }
}

// ---------------------------------------------------------------------------
// seg kernel v7 (unchanged from round 14 — bf16 outputs).
// ---------------------------------------------------------------------------
__global__ __launch_bounds__(256, 8) void seg_kernel(
    const float* __restrict__ x,
    const int*   __restrict__ bnd,
    const float* __restrict__ att_w,
    short* __restrict__ merged_bf,   // (NB, 1024) bf16
    short* __restrict__ center_bf,   // (NB, 256)  bf16
    short* __restrict__ neighbor_bf) // (NB, 256)  bf16
{
    const int b   = blockIdx.x;
    const int tid = threadIdx.x;
    const int w   = tid >> 6;
    const int l   = tid & 63;

    const int start = bnd[b];
    const int end   = bnd[b + 1];

    const int cnt = end - start;
    const int q = cnt >> 2, r = cnt & 3;
    const int my_start = start + w * q + (w < r ? w : r);
    const int my_cnt   = q + (w < r ? 1 : 0);

    const float4 awv = *reinterpret_cast<const float4*>(&att_w[4 * l]);
    const f2 aw01 = {awv.x, awv.y}, aw23 = {awv.z, awv.w};

    f2 c01 = sp(0.f), c23 = sp(0.f);                 // segsum(gelu)
    f2 s01 = sp(0.f), s23 = sp(0.f);                 // segsum(x)
    f2 m01 = sp(-INFINITY), m23 = sp(-INFINITY);     // segmax(x)
    f2 a01 = sp(0.f), a23 = sp(0.f);                 // sum e*x
    float lsum = 0.f;                                 // sum e (per head)

    auto process = [&](const float4& v) {
        f2 vl = {v.x, v.y}, vh = {v.z, v.w};
        f2 gl = gelu2(vl), gh = gelu2(vh);
        c01 += gl; c23 += gh;
        s01 += vl; s23 += vh;
        m01 = __builtin_elementwise_max(m01, vl);
        m23 = __builtin_elementwise_max(m23, vh);
        f2 tp = __builtin_elementwise_fma(vh, aw23, vl * aw01);
        float t = tp.x + tp.y;
        t += __shfl_xor(t, 1, 64);
        t += __shfl_xor(t, 2, 64);
        t += __shfl_xor(t, 4, 64);
        t += __shfl_xor(t, 8, 64);
        float alpha = fmaxf(t, 0.2f * t);   // leaky_relu(0.2)
        float e = __expf(alpha);            // no max-shift: |alpha| small
        lsum += e;
        f2 ev = sp(e);
        a01 = __builtin_elementwise_fma(ev, vl, a01);
        a23 = __builtin_elementwise_fma(ev, vh, a23);
    };

    const float* __restrict__ xl = x + 4 * l;
    auto LD = [&](int row) -> float4 {
        int rc = row < (NN - 1) ? row : (NN - 1);   // clamp: over-reads discarded
        return *reinterpret_cast<const float4*>(&xl[(size_t)rc * DD]);
    };

    float4 q0 = LD(my_start),     q1 = LD(my_start + 1),
           q2 = LD(my_start + 2), q3 = LD(my_start + 3);
    int ip = my_start + 4;
    int rem = my_cnt;
    while (rem >= 2) {
        float4 f0 = LD(ip), f1 = LD(ip + 1);
        process(q0); process(q1);
        q0 = q2; q1 = q3; q2 = f0; q3 = f1;
        ip += 2; rem -= 2;
    }
    if (rem) process(q0);

    __shared__ float lds[4][4][256];
    __shared__ float ldsl[4][4];
    const int c = 4 * l;
    lds[0][w][c+0] = c01.x; lds[0][w][c+1] = c01.y; lds[0][w][c+2] = c23.x; lds[0][w][c+3] = c23.y;
    lds[1][w][c+0] = s01.x; lds[1][w][c+1] = s01.y; lds[1][w][c+2] = s23.x; lds[1][w][c+3] = s23.y;
    lds[2][w][c+0] = m01.x; lds[2][w][c+1] = m01.y; lds[2][w][c+2] = m23.x; lds[2][w][c+3] = m23.y;
    lds[3][w][c+0] = a01.x; lds[3][w][c+1] = a01.y; lds[3][w][c+2] = a23.x; lds[3][w][c+3] = a23.y;
    if ((l & 15) == 0) ldsl[w][l >> 4] = lsum;
    __syncthreads();

    const int d = tid;   // output column
    float cs = lds[0][0][d] + lds[0][1][d] + lds[0][2][d] + lds[0][3][d];
    float ss = lds[1][0][d] + lds[1][1][d] + lds[1][2][d] + lds[1][3][d];
    float mm = fmaxf(fmaxf(lds[2][0][d], lds[2][1][d]), fmaxf(lds[2][2][d], lds[2][3][d]));
    float ac = lds[3][0][d] + lds[3][1][d] + lds[3][2][d] + lds[3][3][d];
    const int h = d >> 6;
    float denom = ldsl[0][h] + ldsl[1][h] + ldsl[2][h] + ldsl[3][h];
    float att = (denom > 0.f) ? ac / denom : 0.f;
    float nm = gelu2((f2){mm, mm}).x;   // neighbor = gelu(segmax(x))

    short* mrow = merged_bf + (size_t)b * 1024;
    mrow[256 + d] = f2bf(att);
    mrow[512 + d] = f2bf(mm);
    mrow[768 + d] = f2bf(ss);
    center_bf  [(size_t)b * DD + d] = f2bf(cs);
    neighbor_bf[(size_t)b * DD + d] = f2bf(nm);
}

// ---------------------------------------------------------------------------
// Fused GRU GEMM v5: BK=64 (4 K-iters, half the barriers of v4). A bf16.
// 64 rows x 16 rnn-cols per block, grid (64,16)=1024 blocks.
// ---------------------------------------------------------------------------
__global__ __launch_bounds__(256) void gemm_gru(
    const short* __restrict__ center_bf,    // (NB, 256) bf16
    const short* __restrict__ neighbor_bf,  // (NB, 256) bf16
    const float* __restrict__ w_ih,         // (768, 256)
    const float* __restrict__ w_hh,         // (768, 256)
    const float* __restrict__ b_ih,         // (768)
    const float* __restrict__ b_hh,         // (768)
    short* __restrict__ merged_bf)          // (NB, 1024) bf16
{
    __shared__ short Ac[64 * 72];
    __shared__ short An[64 * 72];
    __shared__ short Wt[6][16 * 72];

    const int t   = threadIdx.x;
    const int w   = t >> 6, l = t & 63;
    const int m0  = blockIdx.x * 64;
    const int j0  = blockIdx.y * 16;
    const int lr  = t >> 2;              // A row 0..63
    const int lc  = (t & 3) * 16;        // A k-offset (16 shorts)
    const int l15 = l & 15, lq = l >> 4;

    // W staging: 6 float4/thread. f = i*256+t: gate = f>>8, idx = f&255,
    // wrow = idx>>4 (16 f4/row over 64 floats), wk4 = (idx&15)*4.
    int wg[6], wrow[6], wk4[6];
    const float* wbase[6];
    #pragma unroll
    for (int i = 0; i < 6; ++i) {
        int f = i * 256 + t;
        wg[i] = f >> 8;
        int idx = f & 255;
        wrow[i] = idx >> 4;
        wk4[i]  = (idx & 15) * 4;
        wbase[i] = (wg[i] < 3)
            ? &w_ih[(size_t)(wg[i] * 256 + j0 + wrow[i]) * 256 + wk4[i]]
            : &w_hh[(size_t)((wg[i] - 3) * 256 + j0 + wrow[i]) * 256 + wk4[i]];
    }
    const short* crp = &center_bf  [(size_t)(m0 + lr) * 256 + lc];
    const short* nrp = &neighbor_bf[(size_t)(m0 + lr) * 256 + lc];

    floatx4 acc[6] = {};

    short8 c0 = *(const short8*)(crp), c1 = *(const short8*)(crp + 8);
    short8 n0 = *(const short8*)(nrp), n1 = *(const short8*)(nrp + 8);
    float4 wv[6];
    #pragma unroll
    for (int i = 0; i < 6; ++i) wv[i] = *(const float4*)(wbase[i]);

    for (int k0 = 0; k0 < 256; k0 += 64) {
        const int kn = (k0 + 64 < 256) ? k0 + 64 : k0;
        short8 nc0 = *(const short8*)(crp + kn), nc1 = *(const short8*)(crp + kn + 8);
        short8 nn0 = *(const short8*)(nrp + kn), nn1 = *(const short8*)(nrp + kn + 8);
        float4 nwv[6];
        #pragma unroll
        for (int i = 0; i < 6; ++i) nwv[i] = *(const float4*)(wbase[i] + kn);

        short4v w4[6];
        #pragma unroll
        for (int i = 0; i < 6; ++i)
            w4[i] = (short4v){ f2bf(wv[i].x), f2bf(wv[i].y), f2bf(wv[i].z), f2bf(wv[i].w) };

        __syncthreads();
        *(short8*)&Ac[lr * 72 + lc]     = c0;
        *(short8*)&Ac[lr * 72 + lc + 8] = c1;
        *(short8*)&An[lr * 72 + lc]     = n0;
        *(short8*)&An[lr * 72 + lc + 8] = n1;
        #pragma unroll
        for (int i = 0; i < 6; ++i)
            *(short4v*)&Wt[wg[i]][wrow[i] * 72 + wk4[i]] = w4[i];
        __syncthreads();

        short8 afc[2], afn[2];
        #pragma unroll
        for (int ks = 0; ks < 2; ++ks) {
            afc[ks] = *(short8*)&Ac[(w * 16 + l15) * 72 + ks * 32 + lq * 8];
            afn[ks] = *(short8*)&An[(w * 16 + l15) * 72 + ks * 32 + lq * 8];
        }
        #pragma unroll
        for (int gg = 0; gg < 6; ++gg) {
            #pragma unroll
            for (int ks = 0; ks < 2; ++ks) {
                short8 bf = *(short8*)&Wt[gg][l15 * 72 + ks * 32 + lq * 8];
                acc[gg] = __builtin_amdgcn_mfma_f32_16x16x32_bf16(
                    (gg < 3) ? afc[ks] : afn[ks], bf, acc[gg], 0, 0, 0);
            }
        }

        c0 = nc0; c1 = nc1; n0 = nn0; n1 = nn1;
        #pragma unroll
        for (int i = 0; i < 6; ++i) wv[i] = nwv[i];
    }

    const int col = j0 + l15;
    const float bir = b_ih[col], biz = b_ih[256 + col], bin = b_ih[512 + col];
    const float bhr = b_hh[col], bhz = b_hh[256 + col], bhn = b_hh[512 + col];
    #pragma unroll
    for (int qq = 0; qq < 4; ++qq) {
        const int row = m0 + w * 16 + lq * 4 + qq;
        float rr = 1.f / (1.f + __expf(-(acc[0][qq] + bir + acc[3][qq] + bhr)));
        float zz = 1.f / (1.f + __expf(-(acc[1][qq] + biz + acc[4][qq] + bhz)));
        float ng = tanhf(acc[2][qq] + bin + rr * (acc[5][qq] + bhn));
        float nb = bf2f(neighbor_bf[(size_t)row * 256 + col]);
        merged_bf[(size_t)row * 1024 + col] = f2bf((1.f - zz) * ng + zz * nb);
    }
}

// ---------------------------------------------------------------------------
// bf16 MFMA GEMM v5 (merge): 64x64 tile (grid (64,4)=256 blocks), BK=64,
// register dbuf. B-traffic halves vs 32-row tiles (64 MB total); 8 MFMA/iter.
// ---------------------------------------------------------------------------
__global__ __launch_bounds__(256) void gemm_bf16(
    const short* __restrict__ A,          // (NB, 1024) bf16
    const float* __restrict__ W,          // (256, 1024)
    const float* __restrict__ bias,       // (256)
    float* __restrict__ C, int K, int ldc)
{
    __shared__ short As[64 * 72];
    __shared__ short Bs[64 * 72];

    const int t   = threadIdx.x;
    const int w   = t >> 6, l = t & 63;
    const int wm  = w >> 1, wn = w & 1;
    const int m0  = blockIdx.x * 64, n0 = blockIdx.y * 64;
    const int arow = t >> 2, ak = (t & 3) * 16;   // A: 16 shorts/thread
    const int brow = t >> 2, bkf = (t & 3) * 16;  // B: 16 floats/thread
    const int l15 = l & 15, lq = l >> 4;

    const short* ap = &A[(size_t)(m0 + arow) * K + ak];
    const float* bp = &W[(size_t)(n0 + brow) * K + bkf];

    floatx4 acc[2][2] = {};

    short8 a0 = *(const short8*)(ap), a1 = *(const short8*)(ap + 8);
    float4 b0 = *(const float4*)(bp),      b1 = *(const float4*)(bp + 4);
    float4 b2 = *(const float4*)(bp + 8),  b3 = *(const float4*)(bp + 12);

    for (int k0 = 0; k0 < K; k0 += 64) {
        const int kn = (k0 + 64 < K) ? k0 + 64 : k0;
        short8 na0 = *(const short8*)(ap + kn), na1 = *(const short8*)(ap + kn + 8);
        float4 nb0 = *(const float4*)(bp + kn),      nb1 = *(const float4*)(bp + kn + 4);
        float4 nb2 = *(const float4*)(bp + kn + 8),  nb3 = *(const float4*)(bp + kn + 12);

        short8 w80 = { f2bf(b0.x), f2bf(b0.y), f2bf(b0.z), f2bf(b0.w),
                       f2bf(b1.x), f2bf(b1.y), f2bf(b1.z), f2bf(b1.w) };
        short8 w81 = { f2bf(b2.x), f2bf(b2.y), f2bf(b2.z), f2bf(b2.w),
                       f2bf(b3.x), f2bf(b3.y), f2bf(b3.z), f2bf(b3.w) };

        __syncthreads();
        *(short8*)&As[arow * 72 + ak]      = a0;
        *(short8*)&As[arow * 72 + ak + 8]  = a1;
        *(short8*)&Bs[brow * 72 + bkf]     = w80;
        *(short8*)&Bs[brow * 72 + bkf + 8] = w81;
        __syncthreads();

        #pragma unroll
        for (int ks = 0; ks < 2; ++ks) {
            short8 af0 = *(short8*)&As[(wm * 32 +      l15) * 72 + ks * 32 + lq * 8];
            short8 af1 = *(short8*)&As[(wm * 32 + 16 + l15) * 72 + ks * 32 + lq * 8];
            short8 bf0 = *(short8*)&Bs[(wn * 32 +      l15) * 72 + ks * 32 + lq * 8];
            short8 bf1 = *(short8*)&Bs[(wn * 32 + 16 + l15) * 72 + ks * 32 + lq * 8];
            acc[0][0] = __builtin_amdgcn_mfma_f32_16x16x32_bf16(af0, bf0, acc[0][0], 0, 0, 0);
            acc[0][1] = __builtin_amdgcn_mfma_f32_16x16x32_bf16(af0, bf1, acc[0][1], 0, 0, 0);
            acc[1][0] = __builtin_amdgcn_mfma_f32_16x16x32_bf16(af1, bf0, acc[1][0], 0, 0, 0);
            acc[1][1] = __builtin_amdgcn_mfma_f32_16x16x32_bf16(af1, bf1, acc[1][1], 0, 0, 0);
        }

        a0 = na0; a1 = na1; b0 = nb0; b1 = nb1; b2 = nb2; b3 = nb3;
    }

    #pragma unroll
    for (int mi = 0; mi < 2; ++mi) {
        #pragma unroll
        for (int nj = 0; nj < 2; ++nj) {
            const int col = n0 + wn * 32 + 16 * nj + l15;
            const float bv = bias[col];
            #pragma unroll
            for (int qq = 0; qq < 4; ++qq) {
                const int row = m0 + wm * 32 + 16 * mi + lq * 4 + qq;
                C[(size_t)row * ldc + col] = acc[mi][nj][qq] + bv;
            }
        }
    }
}

// ---------------------------------------------------------------------------
extern "C" void kernel_launch(void* const* d_in, const int* in_sizes, int n_in,
                              void* d_out, int out_size, void* d_ws, size_t ws_size,
                              hipStream_t stream) {
    const float* x       = (const float*)d_in[0];
    const int*   seg     = (const int*)  d_in[1];
    const float* att_w   = (const float*)d_in[2];
    const float* w_ih    = (const float*)d_in[3];
    const float* w_hh    = (const float*)d_in[4];
    const float* b_ih    = (const float*)d_in[5];
    const float* b_hh    = (const float*)d_in[6];
    const float* merge_w = (const float*)d_in[7];
    const float* merge_b = (const float*)d_in[8];
    float* out = (float*)d_out;

    // ws layout (bf16 pipeline):
    short* merged_bf   = (short*)d_ws;                       // NB*1024 shorts
    short* center_bf   = merged_bf   + (size_t)NB * 1024;    // NB*256 shorts
    short* neighbor_bf = center_bf   + (size_t)NB * DD;      // NB*256 shorts
    int*   bnd         = (int*)(neighbor_bf + (size_t)NB * DD);  // 4097 ints

    seg_bounds<<<(NN + 255) / 256, 256, 0, stream>>>(seg, bnd);

    seg_kernel<<<NB, 256, 0, stream>>>(x, bnd, att_w, merged_bf, center_bf, neighbor_bf);

    dim3 gg(NB / 64, DD / 16);   // 64 x 16 = 1024 blocks
    gemm_gru<<<gg, 256, 0, stream>>>(center_bf, neighbor_bf, w_ih, w_hh, b_ih, b_hh, merged_bf);

    dim3 g2(NB / 64, DD / 64);   // 64 x 4 = 256 blocks
    gemm_bf16<<<g2, 256, 0, stream>>>(merged_bf, merge_w, merge_b, out, 1024, DD);
}

// Round 16
// 135.010 us; speedup vs baseline: 1.4319x; 1.0387x over previous
//
#include <hip/hip_runtime.h>
#include <math.h>
#include <stdint.h>

#define NN 500000   // nodes
#define NB 4096     // segments
#define DD 256      // feature dim
#define NBND 1954   // ceil(NN/256) blocks for bounds part
#define WPREP 640   // weight-conversion blocks (640*1024 = 655360 floats exactly)

typedef short  short8  __attribute__((ext_vector_type(8)));
typedef short  short4v __attribute__((ext_vector_type(4)));
typedef float  floatx4 __attribute__((ext_vector_type(4)));
typedef float  f2      __attribute__((ext_vector_type(2)));

__device__ __forceinline__ f2 sp(float v) { return (f2){v, v}; }

// fp32 -> bf16 round-to-nearest-even
__device__ __forceinline__ short f2bf(float f) {
    uint32_t u = __float_as_uint(f);
    u += 0x7fffu + ((u >> 16) & 1u);
    return (short)(u >> 16);
}
// bf16 -> fp32
__device__ __forceinline__ float bf2f(short s) {
    uint32_t u = ((uint32_t)(unsigned short)s) << 16;
    return __uint_as_float(u);
}

// Packed gelu via A&S 7.1.28: erf(z) = 1 - (1+a1 z+..+a6 z^6)^-16, |eps|<=3e-7.
__device__ __forceinline__ f2 gelu2(f2 x) {
    f2 z = __builtin_elementwise_abs(x) * sp(0.70710678118654752440f);
    f2 p = __builtin_elementwise_fma(z, sp(0.0000430638f), sp(0.0002765672f));
    p = __builtin_elementwise_fma(p, z, sp(0.0001520143f));
    p = __builtin_elementwise_fma(p, z, sp(0.0092705272f));
    p = __builtin_elementwise_fma(p, z, sp(0.0422820123f));
    p = __builtin_elementwise_fma(p, z, sp(0.0705230784f));
    p = __builtin_elementwise_fma(p, z, sp(1.0f));
    p = p * p; p = p * p; p = p * p; p = p * p;           // p^16
    f2 r = { __builtin_amdgcn_rcpf(p.x), __builtin_amdgcn_rcpf(p.y) };
    f2 er = __builtin_elementwise_copysign(sp(1.0f) - r, x);
    return sp(0.5f) * x * (sp(1.0f) + er);
}

// ---------------------------------------------------------------------------
// Kernel 0: bounds precompute + weight bf16 pre-quantization (fused, zero
// extra launches). Blocks [0,NBND): bnd[]; blocks [NBND,NBND+WPREP): convert
// w_ih/w_hh/merge_w fp32 -> bf16 (4 floats/thread, exact cover).
// ---------------------------------------------------------------------------
__global__ __launch_bounds__(256) void prep_kernel(
    const int*   __restrict__ seg,
    const float* __restrict__ w_ih,     // 196608 floats
    const float* __restrict__ w_hh,     // 196608 floats
    const float* __restrict__ merge_w,  // 262144 floats
    int*   __restrict__ bnd,
    short* __restrict__ wih_bf,
    short* __restrict__ whh_bf,
    short* __restrict__ mw_bf)
{
    const int bid = blockIdx.x;
    const int t   = threadIdx.x;
    if (bid < NBND) {
        int i = bid * 256 + t;
        if (i >= NN) return;
        int s = seg[i];
        if (i == 0) {
            for (int b = 0; b <= s; ++b) bnd[b] = 0;
        } else {
            int p = seg[i - 1];
            for (int b = p + 1; b <= s; ++b) bnd[b] = i;
        }
        if (i == NN - 1) {
            for (int b = s + 1; b <= NB; ++b) bnd[b] = NN;
        }
    } else {
        int base = (bid - NBND) * 1024 + t * 4;
        const float* src; short* dst;
        if (base < 196608)      { src = &w_ih[base];            dst = &wih_bf[base]; }
        else if (base < 393216) { src = &w_hh[base - 196608];   dst = &whh_bf[base - 196608]; }
        else                    { src = &merge_w[base - 393216]; dst = &mw_bf[base - 393216]; }
        float4 v = *(const float4*)src;
        *(short4v*)dst = (short4v){ f2bf(v.x), f2bf(v.y), f2bf(v.z), f2bf(v.w) };
    }
}

// ---------------------------------------------------------------------------
// seg kernel v7 (unchanged from rounds 14/15 — bf16 outputs).
// ---------------------------------------------------------------------------
__global__ __launch_bounds__(256, 8) void seg_kernel(
    const float* __restrict__ x,
    const int*   __restrict__ bnd,
    const float* __restrict__ att_w,
    short* __restrict__ merged_bf,   // (NB, 1024) bf16
    short* __restrict__ center_bf,   // (NB, 256)  bf16
    short* __restrict__ neighbor_bf) // (NB, 256)  bf16
{
    const int b   = blockIdx.x;
    const int tid = threadIdx.x;
    const int w   = tid >> 6;
    const int l   = tid & 63;

    const int start = bnd[b];
    const int end   = bnd[b + 1];

    const int cnt = end - start;
    const int q = cnt >> 2, r = cnt & 3;
    const int my_start = start + w * q + (w < r ? w : r);
    const int my_cnt   = q + (w < r ? 1 : 0);

    const float4 awv = *reinterpret_cast<const float4*>(&att_w[4 * l]);
    const f2 aw01 = {awv.x, awv.y}, aw23 = {awv.z, awv.w};

    f2 c01 = sp(0.f), c23 = sp(0.f);                 // segsum(gelu)
    f2 s01 = sp(0.f), s23 = sp(0.f);                 // segsum(x)
    f2 m01 = sp(-INFINITY), m23 = sp(-INFINITY);     // segmax(x)
    f2 a01 = sp(0.f), a23 = sp(0.f);                 // sum e*x
    float lsum = 0.f;                                 // sum e (per head)

    auto process = [&](const float4& v) {
        f2 vl = {v.x, v.y}, vh = {v.z, v.w};
        f2 gl = gelu2(vl), gh = gelu2(vh);
        c01 += gl; c23 += gh;
        s01 += vl; s23 += vh;
        m01 = __builtin_elementwise_max(m01, vl);
        m23 = __builtin_elementwise_max(m23, vh);
        f2 tp = __builtin_elementwise_fma(vh, aw23, vl * aw01);
        float t = tp.x + tp.y;
        t += __shfl_xor(t, 1, 64);
        t += __shfl_xor(t, 2, 64);
        t += __shfl_xor(t, 4, 64);
        t += __shfl_xor(t, 8, 64);
        float alpha = fmaxf(t, 0.2f * t);   // leaky_relu(0.2)
        float e = __expf(alpha);            // no max-shift: |alpha| small
        lsum += e;
        f2 ev = sp(e);
        a01 = __builtin_elementwise_fma(ev, vl, a01);
        a23 = __builtin_elementwise_fma(ev, vh, a23);
    };

    const float* __restrict__ xl = x + 4 * l;
    auto LD = [&](int row) -> float4 {
        int rc = row < (NN - 1) ? row : (NN - 1);   // clamp: over-reads discarded
        return *reinterpret_cast<const float4*>(&xl[(size_t)rc * DD]);
    };

    float4 q0 = LD(my_start),     q1 = LD(my_start + 1),
           q2 = LD(my_start + 2), q3 = LD(my_start + 3);
    int ip = my_start + 4;
    int rem = my_cnt;
    while (rem >= 2) {
        float4 f0 = LD(ip), f1 = LD(ip + 1);
        process(q0); process(q1);
        q0 = q2; q1 = q3; q2 = f0; q3 = f1;
        ip += 2; rem -= 2;
    }
    if (rem) process(q0);

    __shared__ float lds[4][4][256];
    __shared__ float ldsl[4][4];
    const int c = 4 * l;
    lds[0][w][c+0] = c01.x; lds[0][w][c+1] = c01.y; lds[0][w][c+2] = c23.x; lds[0][w][c+3] = c23.y;
    lds[1][w][c+0] = s01.x; lds[1][w][c+1] = s01.y; lds[1][w][c+2] = s23.x; lds[1][w][c+3] = s23.y;
    lds[2][w][c+0] = m01.x; lds[2][w][c+1] = m01.y; lds[2][w][c+2] = m23.x; lds[2][w][c+3] = m23.y;
    lds[3][w][c+0] = a01.x; lds[3][w][c+1] = a01.y; lds[3][w][c+2] = a23.x; lds[3][w][c+3] = a23.y;
    if ((l & 15) == 0) ldsl[w][l >> 4] = lsum;
    __syncthreads();

    const int d = tid;   // output column
    float cs = lds[0][0][d] + lds[0][1][d] + lds[0][2][d] + lds[0][3][d];
    float ss = lds[1][0][d] + lds[1][1][d] + lds[1][2][d] + lds[1][3][d];
    float mm = fmaxf(fmaxf(lds[2][0][d], lds[2][1][d]), fmaxf(lds[2][2][d], lds[2][3][d]));
    float ac = lds[3][0][d] + lds[3][1][d] + lds[3][2][d] + lds[3][3][d];
    const int h = d >> 6;
    float denom = ldsl[0][h] + ldsl[1][h] + ldsl[2][h] + ldsl[3][h];
    float att = (denom > 0.f) ? ac / denom : 0.f;
    float nm = gelu2((f2){mm, mm}).x;   // neighbor = gelu(segmax(x))

    short* mrow = merged_bf + (size_t)b * 1024;
    mrow[256 + d] = f2bf(att);
    mrow[512 + d] = f2bf(mm);
    mrow[768 + d] = f2bf(ss);
    center_bf  [(size_t)b * DD + d] = f2bf(cs);
    neighbor_bf[(size_t)b * DD + d] = f2bf(nm);
}

// ---------------------------------------------------------------------------
// Fused kernel: blocks [0,1024) = GRU GEMM (64 rows x 16 rnn-cols, K=256,
// BK=64, all-bf16 operands); blocks [1024,1280) = base-merge GEMM
// out = merged[:,256:1024] @ W[:,256:1024]^T + bias (64x64 tile, K=768).
// The two populations are independent (disjoint merged columns) and
// co-schedule on the CUs instead of serializing across a launch boundary.
// ---------------------------------------------------------------------------
__global__ __launch_bounds__(256) void gru_and_basemerge(
    const short* __restrict__ center_bf,    // (NB, 256) bf16
    const short* __restrict__ neighbor_bf,  // (NB, 256) bf16
    const short* __restrict__ wih_bf,       // (768, 256) bf16
    const short* __restrict__ whh_bf,       // (768, 256) bf16
    const float* __restrict__ b_ih,         // (768)
    const float* __restrict__ b_hh,         // (768)
    short* __restrict__ merged_bf,          // (NB, 1024) bf16 (rnn slice written)
    const short* __restrict__ mw_bf,        // (256, 1024) bf16
    const float* __restrict__ merge_b,      // (256)
    float* __restrict__ out)                // (NB, 256)
{
    __shared__ short smem[16128];            // union: gru 16128, merge 9216 shorts
    const int t   = threadIdx.x;
    const int w   = t >> 6, l = t & 63;
    const int l15 = l & 15, lq = l >> 4;

    if (blockIdx.x < 1024) {
        // ---------------- GRU part ----------------
        short* Ac = smem;                    // 64*72
        short* An = smem + 4608;             // 64*72
        short* Wt = smem + 9216;             // 6*16*72

        const int m0 = (blockIdx.x >> 4) * 64;
        const int j0 = (blockIdx.x & 15) * 16;
        const int lr = t >> 2;               // A row 0..63
        const int lc = (t & 3) * 16;         // A k-offset (16 shorts)

        // W staging: 3 short8/thread. f = i*256+t over 768 slots;
        // 128 slots/gate (16 rows x 8 short8). wg=f>>7, wrow=(f&127)>>3, wk8=(f&7)*8.
        int wg[3], wrow[3], wk8[3];
        const short* wbase[3];
        #pragma unroll
        for (int i = 0; i < 3; ++i) {
            int f = i * 256 + t;
            wg[i]  = f >> 7;
            int idx = f & 127;
            wrow[i] = idx >> 3;
            wk8[i]  = (idx & 7) * 8;
            wbase[i] = (wg[i] < 3)
                ? &wih_bf[(size_t)(wg[i] * 256 + j0 + wrow[i]) * 256 + wk8[i]]
                : &whh_bf[(size_t)((wg[i] - 3) * 256 + j0 + wrow[i]) * 256 + wk8[i]];
        }
        const short* crp = &center_bf  [(size_t)(m0 + lr) * 256 + lc];
        const short* nrp = &neighbor_bf[(size_t)(m0 + lr) * 256 + lc];

        floatx4 acc[6] = {};

        short8 c0 = *(const short8*)(crp), c1 = *(const short8*)(crp + 8);
        short8 n0 = *(const short8*)(nrp), n1 = *(const short8*)(nrp + 8);
        short8 wv0 = *(const short8*)(wbase[0]);
        short8 wv1 = *(const short8*)(wbase[1]);
        short8 wv2 = *(const short8*)(wbase[2]);

        for (int k0 = 0; k0 < 256; k0 += 64) {
            const int kn = (k0 + 64 < 256) ? k0 + 64 : k0;
            short8 nc0 = *(const short8*)(crp + kn), nc1 = *(const short8*)(crp + kn + 8);
            short8 nn0 = *(const short8*)(nrp + kn), nn1 = *(const short8*)(nrp + kn + 8);
            short8 nw0 = *(const short8*)(wbase[0] + kn);
            short8 nw1 = *(const short8*)(wbase[1] + kn);
            short8 nw2 = *(const short8*)(wbase[2] + kn);

            __syncthreads();
            *(short8*)&Ac[lr * 72 + lc]     = c0;
            *(short8*)&Ac[lr * 72 + lc + 8] = c1;
            *(short8*)&An[lr * 72 + lc]     = n0;
            *(short8*)&An[lr * 72 + lc + 8] = n1;
            *(short8*)&Wt[wg[0] * 1152 + wrow[0] * 72 + wk8[0]] = wv0;
            *(short8*)&Wt[wg[1] * 1152 + wrow[1] * 72 + wk8[1]] = wv1;
            *(short8*)&Wt[wg[2] * 1152 + wrow[2] * 72 + wk8[2]] = wv2;
            __syncthreads();

            short8 afc[2], afn[2];
            #pragma unroll
            for (int ks = 0; ks < 2; ++ks) {
                afc[ks] = *(short8*)&Ac[(w * 16 + l15) * 72 + ks * 32 + lq * 8];
                afn[ks] = *(short8*)&An[(w * 16 + l15) * 72 + ks * 32 + lq * 8];
            }
            #pragma unroll
            for (int gg = 0; gg < 6; ++gg) {
                #pragma unroll
                for (int ks = 0; ks < 2; ++ks) {
                    short8 bf = *(short8*)&Wt[gg * 1152 + l15 * 72 + ks * 32 + lq * 8];
                    acc[gg] = __builtin_amdgcn_mfma_f32_16x16x32_bf16(
                        (gg < 3) ? afc[ks] : afn[ks], bf, acc[gg], 0, 0, 0);
                }
            }

            c0 = nc0; c1 = nc1; n0 = nn0; n1 = nn1;
            wv0 = nw0; wv1 = nw1; wv2 = nw2;
        }

        const int col = j0 + l15;
        const float bir = b_ih[col], biz = b_ih[256 + col], bin = b_ih[512 + col];
        const float bhr = b_hh[col], bhz = b_hh[256 + col], bhn = b_hh[512 + col];
        #pragma unroll
        for (int qq = 0; qq < 4; ++qq) {
            const int row = m0 + w * 16 + lq * 4 + qq;
            float rr = 1.f / (1.f + __expf(-(acc[0][qq] + bir + acc[3][qq] + bhr)));
            float zz = 1.f / (1.f + __expf(-(acc[1][qq] + biz + acc[4][qq] + bhz)));
            float ng = tanhf(acc[2][qq] + bin + rr * (acc[5][qq] + bhn));
            float nb = bf2f(neighbor_bf[(size_t)row * 256 + col]);
            merged_bf[(size_t)row * 1024 + col] = f2bf((1.f - zz) * ng + zz * nb);
        }
    } else {
        // ---------------- base-merge part (K=768, cols 256..1024) ----------------
        short* As = smem;                    // 64*72
        short* Bs = smem + 4608;             // 64*72

        const int bid2 = blockIdx.x - 1024;  // 0..255
        const int m0 = (bid2 & 63) * 64, n0 = (bid2 >> 6) * 64;
        const int arow = t >> 2, ak = (t & 3) * 16;
        const int wm = w >> 1, wn = w & 1;

        const short* ap = &merged_bf[(size_t)(m0 + arow) * 1024 + 256 + ak];
        const short* bp = &mw_bf    [(size_t)(n0 + arow) * 1024 + 256 + ak];

        floatx4 acc[2][2] = {};

        short8 a0 = *(const short8*)(ap), a1 = *(const short8*)(ap + 8);
        short8 b0 = *(const short8*)(bp), b1 = *(const short8*)(bp + 8);

        for (int k0 = 0; k0 < 768; k0 += 64) {
            const int kn = (k0 + 64 < 768) ? k0 + 64 : k0;
            short8 na0 = *(const short8*)(ap + kn), na1 = *(const short8*)(ap + kn + 8);
            short8 nb0 = *(const short8*)(bp + kn), nb1 = *(const short8*)(bp + kn + 8);

            __syncthreads();
            *(short8*)&As[arow * 72 + ak]     = a0;
            *(short8*)&As[arow * 72 + ak + 8] = a1;
            *(short8*)&Bs[arow * 72 + ak]     = b0;
            *(short8*)&Bs[arow * 72 + ak + 8] = b1;
            __syncthreads();

            #pragma unroll
            for (int ks = 0; ks < 2; ++ks) {
                short8 af0 = *(short8*)&As[(wm * 32 +      l15) * 72 + ks * 32 + lq * 8];
                short8 af1 = *(short8*)&As[(wm * 32 + 16 + l15) * 72 + ks * 32 + lq * 8];
                short8 bf0 = *(short8*)&Bs[(wn * 32 +      l15) * 72 + ks * 32 + lq * 8];
                short8 bf1 = *(short8*)&Bs[(wn * 32 + 16 + l15) * 72 + ks * 32 + lq * 8];
                acc[0][0] = __builtin_amdgcn_mfma_f32_16x16x32_bf16(af0, bf0, acc[0][0], 0, 0, 0);
                acc[0][1] = __builtin_amdgcn_mfma_f32_16x16x32_bf16(af0, bf1, acc[0][1], 0, 0, 0);
                acc[1][0] = __builtin_amdgcn_mfma_f32_16x16x32_bf16(af1, bf0, acc[1][0], 0, 0, 0);
                acc[1][1] = __builtin_amdgcn_mfma_f32_16x16x32_bf16(af1, bf1, acc[1][1], 0, 0, 0);
            }

            a0 = na0; a1 = na1; b0 = nb0; b1 = nb1;
        }

        #pragma unroll
        for (int mi = 0; mi < 2; ++mi) {
            #pragma unroll
            for (int nj = 0; nj < 2; ++nj) {
                const int col = n0 + wn * 32 + 16 * nj + l15;
                const float bv = merge_b[col];
                #pragma unroll
                for (int qq = 0; qq < 4; ++qq) {
                    const int row = m0 + wm * 32 + 16 * mi + lq * 4 + qq;
                    out[(size_t)row * 256 + col] = acc[mi][nj][qq] + bv;
                }
            }
        }
    }
}

// ---------------------------------------------------------------------------
// rnn-merge epilogue: out += merged[:,0:256] @ W[:,0:256]^T (K=256).
// 64x64 tile, 256 blocks, BK=64 (4 iters), all-bf16 operands, RMW on out.
// ---------------------------------------------------------------------------
__global__ __launch_bounds__(256) void rnn_merge(
    const short* __restrict__ merged_bf,   // (NB, 1024) bf16
    const short* __restrict__ mw_bf,       // (256, 1024) bf16
    float* __restrict__ out)               // (NB, 256)
{
    __shared__ short As[64 * 72];
    __shared__ short Bs[64 * 72];

    const int t   = threadIdx.x;
    const int w   = t >> 6, l = t & 63;
    const int wm  = w >> 1, wn = w & 1;
    const int m0  = (blockIdx.x & 63) * 64, n0 = (blockIdx.x >> 6) * 64;
    const int arow = t >> 2, ak = (t & 3) * 16;
    const int l15 = l & 15, lq = l >> 4;

    const short* ap = &merged_bf[(size_t)(m0 + arow) * 1024 + ak];
    const short* bp = &mw_bf    [(size_t)(n0 + arow) * 1024 + ak];

    floatx4 acc[2][2] = {};

    short8 a0 = *(const short8*)(ap), a1 = *(const short8*)(ap + 8);
    short8 b0 = *(const short8*)(bp), b1 = *(const short8*)(bp + 8);

    for (int k0 = 0; k0 < 256; k0 += 64) {
        const int kn = (k0 + 64 < 256) ? k0 + 64 : k0;
        short8 na0 = *(const short8*)(ap + kn), na1 = *(const short8*)(ap + kn + 8);
        short8 nb0 = *(const short8*)(bp + kn), nb1 = *(const short8*)(bp + kn + 8);

        __syncthreads();
        *(short8*)&As[arow * 72 + ak]     = a0;
        *(short8*)&As[arow * 72 + ak + 8] = a1;
        *(short8*)&Bs[arow * 72 + ak]     = b0;
        *(short8*)&Bs[arow * 72 + ak + 8] = b1;
        __syncthreads();

        #pragma unroll
        for (int ks = 0; ks < 2; ++ks) {
            short8 af0 = *(short8*)&As[(wm * 32 +      l15) * 72 + ks * 32 + lq * 8];
            short8 af1 = *(short8*)&As[(wm * 32 + 16 + l15) * 72 + ks * 32 + lq * 8];
            short8 bf0 = *(short8*)&Bs[(wn * 32 +      l15) * 72 + ks * 32 + lq * 8];
            short8 bf1 = *(short8*)&Bs[(wn * 32 + 16 + l15) * 72 + ks * 32 + lq * 8];
            acc[0][0] = __builtin_amdgcn_mfma_f32_16x16x32_bf16(af0, bf0, acc[0][0], 0, 0, 0);
            acc[0][1] = __builtin_amdgcn_mfma_f32_16x16x32_bf16(af0, bf1, acc[0][1], 0, 0, 0);
            acc[1][0] = __builtin_amdgcn_mfma_f32_16x16x32_bf16(af1, bf0, acc[1][0], 0, 0, 0);
            acc[1][1] = __builtin_amdgcn_mfma_f32_16x16x32_bf16(af1, bf1, acc[1][1], 0, 0, 0);
        }

        a0 = na0; a1 = na1; b0 = nb0; b1 = nb1;
    }

    #pragma unroll
    for (int mi = 0; mi < 2; ++mi) {
        #pragma unroll
        for (int nj = 0; nj < 2; ++nj) {
            const int col = n0 + wn * 32 + 16 * nj + l15;
            #pragma unroll
            for (int qq = 0; qq < 4; ++qq) {
                const int row = m0 + wm * 32 + 16 * mi + lq * 4 + qq;
                out[(size_t)row * 256 + col] += acc[mi][nj][qq];
            }
        }
    }
}

// ---------------------------------------------------------------------------
extern "C" void kernel_launch(void* const* d_in, const int* in_sizes, int n_in,
                              void* d_out, int out_size, void* d_ws, size_t ws_size,
                              hipStream_t stream) {
    const float* x       = (const float*)d_in[0];
    const int*   seg     = (const int*)  d_in[1];
    const float* att_w   = (const float*)d_in[2];
    const float* w_ih    = (const float*)d_in[3];
    const float* w_hh    = (const float*)d_in[4];
    const float* b_ih    = (const float*)d_in[5];
    const float* b_hh    = (const float*)d_in[6];
    const float* merge_w = (const float*)d_in[7];
    const float* merge_b = (const float*)d_in[8];
    float* out = (float*)d_out;

    // ws layout (bf16 pipeline):
    short* merged_bf   = (short*)d_ws;                       // NB*1024 shorts
    short* center_bf   = merged_bf   + (size_t)NB * 1024;    // NB*256 shorts
    short* neighbor_bf = center_bf   + (size_t)NB * DD;      // NB*256 shorts
    int*   bnd         = (int*)(neighbor_bf + (size_t)NB * DD);  // 8192 ints (4097 used)
    short* wih_bf      = (short*)(bnd + 8192);               // 196608 shorts
    short* whh_bf      = wih_bf + 196608;                    // 196608 shorts
    short* mw_bf       = whh_bf + 196608;                    // 262144 shorts

    prep_kernel<<<NBND + WPREP, 256, 0, stream>>>(
        seg, w_ih, w_hh, merge_w, bnd, wih_bf, whh_bf, mw_bf);

    seg_kernel<<<NB, 256, 0, stream>>>(x, bnd, att_w, merged_bf, center_bf, neighbor_bf);

    gru_and_basemerge<<<1024 + 256, 256, 0, stream>>>(
        center_bf, neighbor_bf, wih_bf, whh_bf, b_ih, b_hh,
        merged_bf, mw_bf, merge_b, out);

    rnn_merge<<<256, 256, 0, stream>>>(merged_bf, mw_bf, out);
}

// Round 17
// 133.313 us; speedup vs baseline: 1.4501x; 1.0127x over previous
//
#include <hip/hip_runtime.h>
#include <math.h>
#include <stdint.h>

#define NN 500000   // nodes
#define NB 4096     // segments
#define DD 256      // feature dim
#define NBND 1954   // ceil(NN/256) blocks for bounds
#define WPREP 640   // weight-conversion blocks (640*1024 = 655360 floats exactly)

typedef short  short8  __attribute__((ext_vector_type(8)));
typedef short  short4v __attribute__((ext_vector_type(4)));
typedef float  floatx4 __attribute__((ext_vector_type(4)));
typedef float  f2      __attribute__((ext_vector_type(2)));

__device__ __forceinline__ f2 sp(float v) { return (f2){v, v}; }

// fp32 -> bf16 round-to-nearest-even
__device__ __forceinline__ short f2bf(float f) {
    uint32_t u = __float_as_uint(f);
    u += 0x7fffu + ((u >> 16) & 1u);
    return (short)(u >> 16);
}
// bf16 -> fp32
__device__ __forceinline__ float bf2f(short s) {
    uint32_t u = ((uint32_t)(unsigned short)s) << 16;
    return __uint_as_float(u);
}

// Packed gelu via A&S 7.1.28: erf(z) = 1 - (1+a1 z+..+a6 z^6)^-16, |eps|<=3e-7.
__device__ __forceinline__ f2 gelu2(f2 x) {
    f2 z = __builtin_elementwise_abs(x) * sp(0.70710678118654752440f);
    f2 p = __builtin_elementwise_fma(z, sp(0.0000430638f), sp(0.0002765672f));
    p = __builtin_elementwise_fma(p, z, sp(0.0001520143f));
    p = __builtin_elementwise_fma(p, z, sp(0.0092705272f));
    p = __builtin_elementwise_fma(p, z, sp(0.0422820123f));
    p = __builtin_elementwise_fma(p, z, sp(0.0705230784f));
    p = __builtin_elementwise_fma(p, z, sp(1.0f));
    p = p * p; p = p * p; p = p * p; p = p * p;           // p^16
    f2 r = { __builtin_amdgcn_rcpf(p.x), __builtin_amdgcn_rcpf(p.y) };
    f2 er = __builtin_elementwise_copysign(sp(1.0f) - r, x);
    return sp(0.5f) * x * (sp(1.0f) + er);
}

// ---------------------------------------------------------------------------
// Kernel 0: bounds precompute only (weight conversion moved into seg launch).
// ---------------------------------------------------------------------------
__global__ __launch_bounds__(256) void seg_bounds(
    const int* __restrict__ seg, int* __restrict__ bnd)
{
    int i = blockIdx.x * 256 + threadIdx.x;
    if (i >= NN) return;
    int s = seg[i];
    if (i == 0) {
        for (int b = 0; b <= s; ++b) bnd[b] = 0;
    } else {
        int p = seg[i - 1];
        for (int b = p + 1; b <= s; ++b) bnd[b] = i;
    }
    if (i == NN - 1) {
        for (int b = s + 1; b <= NB; ++b) bnd[b] = NN;
    }
}

// ---------------------------------------------------------------------------
// seg kernel v8: blocks [0,NB) = seg v7 (unchanged math, bf16 outputs);
// blocks [NB, NB+WPREP) = weight fp32->bf16 conversion (no dependency on seg;
// fills CU bubbles during seg's tail instead of serializing in prep).
// ---------------------------------------------------------------------------
__global__ __launch_bounds__(256, 8) void seg_kernel(
    const float* __restrict__ x,
    const int*   __restrict__ bnd,
    const float* __restrict__ att_w,
    const float* __restrict__ w_ih,
    const float* __restrict__ w_hh,
    const float* __restrict__ merge_w,
    short* __restrict__ merged_bf,   // (NB, 1024) bf16
    short* __restrict__ center_bf,   // (NB, 256)  bf16
    short* __restrict__ neighbor_bf, // (NB, 256)  bf16
    short* __restrict__ wih_bf,
    short* __restrict__ whh_bf,
    short* __restrict__ mw_bf)
{
    const int tid = threadIdx.x;

    if (blockIdx.x >= NB) {
        // ---- weight conversion part ----
        int base = (blockIdx.x - NB) * 1024 + tid * 4;
        const float* src; short* dst;
        if (base < 196608)      { src = &w_ih[base];             dst = &wih_bf[base]; }
        else if (base < 393216) { src = &w_hh[base - 196608];    dst = &whh_bf[base - 196608]; }
        else                    { src = &merge_w[base - 393216]; dst = &mw_bf[base - 393216]; }
        float4 v = *(const float4*)src;
        *(short4v*)dst = (short4v){ f2bf(v.x), f2bf(v.y), f2bf(v.z), f2bf(v.w) };
        return;
    }

    const int b   = blockIdx.x;
    const int w   = tid >> 6;
    const int l   = tid & 63;

    const int start = bnd[b];
    const int end   = bnd[b + 1];

    const int cnt = end - start;
    const int q = cnt >> 2, r = cnt & 3;
    const int my_start = start + w * q + (w < r ? w : r);
    const int my_cnt   = q + (w < r ? 1 : 0);

    const float4 awv = *reinterpret_cast<const float4*>(&att_w[4 * l]);
    const f2 aw01 = {awv.x, awv.y}, aw23 = {awv.z, awv.w};

    f2 c01 = sp(0.f), c23 = sp(0.f);                 // segsum(gelu)
    f2 s01 = sp(0.f), s23 = sp(0.f);                 // segsum(x)
    f2 m01 = sp(-INFINITY), m23 = sp(-INFINITY);     // segmax(x)
    f2 a01 = sp(0.f), a23 = sp(0.f);                 // sum e*x
    float lsum = 0.f;                                 // sum e (per head)

    auto process = [&](const float4& v) {
        f2 vl = {v.x, v.y}, vh = {v.z, v.w};
        f2 gl = gelu2(vl), gh = gelu2(vh);
        c01 += gl; c23 += gh;
        s01 += vl; s23 += vh;
        m01 = __builtin_elementwise_max(m01, vl);
        m23 = __builtin_elementwise_max(m23, vh);
        f2 tp = __builtin_elementwise_fma(vh, aw23, vl * aw01);
        float t = tp.x + tp.y;
        t += __shfl_xor(t, 1, 64);
        t += __shfl_xor(t, 2, 64);
        t += __shfl_xor(t, 4, 64);
        t += __shfl_xor(t, 8, 64);
        float alpha = fmaxf(t, 0.2f * t);   // leaky_relu(0.2)
        float e = __expf(alpha);            // no max-shift: |alpha| small
        lsum += e;
        f2 ev = sp(e);
        a01 = __builtin_elementwise_fma(ev, vl, a01);
        a23 = __builtin_elementwise_fma(ev, vh, a23);
    };

    const float* __restrict__ xl = x + 4 * l;
    auto LD = [&](int row) -> float4 {
        int rc = row < (NN - 1) ? row : (NN - 1);   // clamp: over-reads discarded
        return *reinterpret_cast<const float4*>(&xl[(size_t)rc * DD]);
    };

    float4 q0 = LD(my_start),     q1 = LD(my_start + 1),
           q2 = LD(my_start + 2), q3 = LD(my_start + 3);
    int ip = my_start + 4;
    int rem = my_cnt;
    while (rem >= 2) {
        float4 f0 = LD(ip), f1 = LD(ip + 1);
        process(q0); process(q1);
        q0 = q2; q1 = q3; q2 = f0; q3 = f1;
        ip += 2; rem -= 2;
    }
    if (rem) process(q0);

    __shared__ float lds[4][4][256];
    __shared__ float ldsl[4][4];
    const int c = 4 * l;
    lds[0][w][c+0] = c01.x; lds[0][w][c+1] = c01.y; lds[0][w][c+2] = c23.x; lds[0][w][c+3] = c23.y;
    lds[1][w][c+0] = s01.x; lds[1][w][c+1] = s01.y; lds[1][w][c+2] = s23.x; lds[1][w][c+3] = s23.y;
    lds[2][w][c+0] = m01.x; lds[2][w][c+1] = m01.y; lds[2][w][c+2] = m23.x; lds[2][w][c+3] = m23.y;
    lds[3][w][c+0] = a01.x; lds[3][w][c+1] = a01.y; lds[3][w][c+2] = a23.x; lds[3][w][c+3] = a23.y;
    if ((l & 15) == 0) ldsl[w][l >> 4] = lsum;
    __syncthreads();

    const int d = tid;   // output column
    float cs = lds[0][0][d] + lds[0][1][d] + lds[0][2][d] + lds[0][3][d];
    float ss = lds[1][0][d] + lds[1][1][d] + lds[1][2][d] + lds[1][3][d];
    float mm = fmaxf(fmaxf(lds[2][0][d], lds[2][1][d]), fmaxf(lds[2][2][d], lds[2][3][d]));
    float ac = lds[3][0][d] + lds[3][1][d] + lds[3][2][d] + lds[3][3][d];
    const int h = d >> 6;
    float denom = ldsl[0][h] + ldsl[1][h] + ldsl[2][h] + ldsl[3][h];
    float att = (denom > 0.f) ? ac / denom : 0.f;
    float nm = gelu2((f2){mm, mm}).x;   // neighbor = gelu(segmax(x))

    short* mrow = merged_bf + (size_t)b * 1024;
    mrow[256 + d] = f2bf(att);
    mrow[512 + d] = f2bf(mm);
    mrow[768 + d] = f2bf(ss);
    center_bf  [(size_t)b * DD + d] = f2bf(cs);
    neighbor_bf[(size_t)b * DD + d] = f2bf(nm);
}

// ---------------------------------------------------------------------------
// Fused kernel (unchanged from round 16): blocks [0,1024) = GRU GEMM;
// blocks [1024,1280) = base-merge GEMM (K=768, cols 256..1024).
// ---------------------------------------------------------------------------
__global__ __launch_bounds__(256) void gru_and_basemerge(
    const short* __restrict__ center_bf,    // (NB, 256) bf16
    const short* __restrict__ neighbor_bf,  // (NB, 256) bf16
    const short* __restrict__ wih_bf,       // (768, 256) bf16
    const short* __restrict__ whh_bf,       // (768, 256) bf16
    const float* __restrict__ b_ih,         // (768)
    const float* __restrict__ b_hh,         // (768)
    short* __restrict__ merged_bf,          // (NB, 1024) bf16 (rnn slice written)
    const short* __restrict__ mw_bf,        // (256, 1024) bf16
    const float* __restrict__ merge_b,      // (256)
    float* __restrict__ out)                // (NB, 256)
{
    __shared__ short smem[16128];            // union: gru 16128, merge 9216 shorts
    const int t   = threadIdx.x;
    const int w   = t >> 6, l = t & 63;
    const int l15 = l & 15, lq = l >> 4;

    if (blockIdx.x < 1024) {
        // ---------------- GRU part ----------------
        short* Ac = smem;                    // 64*72
        short* An = smem + 4608;             // 64*72
        short* Wt = smem + 9216;             // 6*16*72

        const int m0 = (blockIdx.x >> 4) * 64;
        const int j0 = (blockIdx.x & 15) * 16;
        const int lr = t >> 2;               // A row 0..63
        const int lc = (t & 3) * 16;         // A k-offset (16 shorts)

        int wg[3], wrow[3], wk8[3];
        const short* wbase[3];
        #pragma unroll
        for (int i = 0; i < 3; ++i) {
            int f = i * 256 + t;
            wg[i]  = f >> 7;
            int idx = f & 127;
            wrow[i] = idx >> 3;
            wk8[i]  = (idx & 7) * 8;
            wbase[i] = (wg[i] < 3)
                ? &wih_bf[(size_t)(wg[i] * 256 + j0 + wrow[i]) * 256 + wk8[i]]
                : &whh_bf[(size_t)((wg[i] - 3) * 256 + j0 + wrow[i]) * 256 + wk8[i]];
        }
        const short* crp = &center_bf  [(size_t)(m0 + lr) * 256 + lc];
        const short* nrp = &neighbor_bf[(size_t)(m0 + lr) * 256 + lc];

        floatx4 acc[6] = {};

        short8 c0 = *(const short8*)(crp), c1 = *(const short8*)(crp + 8);
        short8 n0 = *(const short8*)(nrp), n1 = *(const short8*)(nrp + 8);
        short8 wv0 = *(const short8*)(wbase[0]);
        short8 wv1 = *(const short8*)(wbase[1]);
        short8 wv2 = *(const short8*)(wbase[2]);

        for (int k0 = 0; k0 < 256; k0 += 64) {
            const int kn = (k0 + 64 < 256) ? k0 + 64 : k0;
            short8 nc0 = *(const short8*)(crp + kn), nc1 = *(const short8*)(crp + kn + 8);
            short8 nn0 = *(const short8*)(nrp + kn), nn1 = *(const short8*)(nrp + kn + 8);
            short8 nw0 = *(const short8*)(wbase[0] + kn);
            short8 nw1 = *(const short8*)(wbase[1] + kn);
            short8 nw2 = *(const short8*)(wbase[2] + kn);

            __syncthreads();
            *(short8*)&Ac[lr * 72 + lc]     = c0;
            *(short8*)&Ac[lr * 72 + lc + 8] = c1;
            *(short8*)&An[lr * 72 + lc]     = n0;
            *(short8*)&An[lr * 72 + lc + 8] = n1;
            *(short8*)&Wt[wg[0] * 1152 + wrow[0] * 72 + wk8[0]] = wv0;
            *(short8*)&Wt[wg[1] * 1152 + wrow[1] * 72 + wk8[1]] = wv1;
            *(short8*)&Wt[wg[2] * 1152 + wrow[2] * 72 + wk8[2]] = wv2;
            __syncthreads();

            short8 afc[2], afn[2];
            #pragma unroll
            for (int ks = 0; ks < 2; ++ks) {
                afc[ks] = *(short8*)&Ac[(w * 16 + l15) * 72 + ks * 32 + lq * 8];
                afn[ks] = *(short8*)&An[(w * 16 + l15) * 72 + ks * 32 + lq * 8];
            }
            #pragma unroll
            for (int gg = 0; gg < 6; ++gg) {
                #pragma unroll
                for (int ks = 0; ks < 2; ++ks) {
                    short8 bf = *(short8*)&Wt[gg * 1152 + l15 * 72 + ks * 32 + lq * 8];
                    acc[gg] = __builtin_amdgcn_mfma_f32_16x16x32_bf16(
                        (gg < 3) ? afc[ks] : afn[ks], bf, acc[gg], 0, 0, 0);
                }
            }

            c0 = nc0; c1 = nc1; n0 = nn0; n1 = nn1;
            wv0 = nw0; wv1 = nw1; wv2 = nw2;
        }

        const int col = j0 + l15;
        const float bir = b_ih[col], biz = b_ih[256 + col], bin = b_ih[512 + col];
        const float bhr = b_hh[col], bhz = b_hh[256 + col], bhn = b_hh[512 + col];
        #pragma unroll
        for (int qq = 0; qq < 4; ++qq) {
            const int row = m0 + w * 16 + lq * 4 + qq;
            float rr = 1.f / (1.f + __expf(-(acc[0][qq] + bir + acc[3][qq] + bhr)));
            float zz = 1.f / (1.f + __expf(-(acc[1][qq] + biz + acc[4][qq] + bhz)));
            float ng = tanhf(acc[2][qq] + bin + rr * (acc[5][qq] + bhn));
            float nb = bf2f(neighbor_bf[(size_t)row * 256 + col]);
            merged_bf[(size_t)row * 1024 + col] = f2bf((1.f - zz) * ng + zz * nb);
        }
    } else {
        // ---------------- base-merge part (K=768, cols 256..1024) ----------------
        short* As = smem;                    // 64*72
        short* Bs = smem + 4608;             // 64*72

        const int bid2 = blockIdx.x - 1024;  // 0..255
        const int m0 = (bid2 & 63) * 64, n0 = (bid2 >> 6) * 64;
        const int arow = t >> 2, ak = (t & 3) * 16;
        const int wm = w >> 1, wn = w & 1;

        const short* ap = &merged_bf[(size_t)(m0 + arow) * 1024 + 256 + ak];
        const short* bp = &mw_bf    [(size_t)(n0 + arow) * 1024 + 256 + ak];

        floatx4 acc[2][2] = {};

        short8 a0 = *(const short8*)(ap), a1 = *(const short8*)(ap + 8);
        short8 b0 = *(const short8*)(bp), b1 = *(const short8*)(bp + 8);

        for (int k0 = 0; k0 < 768; k0 += 64) {
            const int kn = (k0 + 64 < 768) ? k0 + 64 : k0;
            short8 na0 = *(const short8*)(ap + kn), na1 = *(const short8*)(ap + kn + 8);
            short8 nb0 = *(const short8*)(bp + kn), nb1 = *(const short8*)(bp + kn + 8);

            __syncthreads();
            *(short8*)&As[arow * 72 + ak]     = a0;
            *(short8*)&As[arow * 72 + ak + 8] = a1;
            *(short8*)&Bs[arow * 72 + ak]     = b0;
            *(short8*)&Bs[arow * 72 + ak + 8] = b1;
            __syncthreads();

            #pragma unroll
            for (int ks = 0; ks < 2; ++ks) {
                short8 af0 = *(short8*)&As[(wm * 32 +      l15) * 72 + ks * 32 + lq * 8];
                short8 af1 = *(short8*)&As[(wm * 32 + 16 + l15) * 72 + ks * 32 + lq * 8];
                short8 bf0 = *(short8*)&Bs[(wn * 32 +      l15) * 72 + ks * 32 + lq * 8];
                short8 bf1 = *(short8*)&Bs[(wn * 32 + 16 + l15) * 72 + ks * 32 + lq * 8];
                acc[0][0] = __builtin_amdgcn_mfma_f32_16x16x32_bf16(af0, bf0, acc[0][0], 0, 0, 0);
                acc[0][1] = __builtin_amdgcn_mfma_f32_16x16x32_bf16(af0, bf1, acc[0][1], 0, 0, 0);
                acc[1][0] = __builtin_amdgcn_mfma_f32_16x16x32_bf16(af1, bf0, acc[1][0], 0, 0, 0);
                acc[1][1] = __builtin_amdgcn_mfma_f32_16x16x32_bf16(af1, bf1, acc[1][1], 0, 0, 0);
            }

            a0 = na0; a1 = na1; b0 = nb0; b1 = nb1;
        }

        #pragma unroll
        for (int mi = 0; mi < 2; ++mi) {
            #pragma unroll
            for (int nj = 0; nj < 2; ++nj) {
                const int col = n0 + wn * 32 + 16 * nj + l15;
                const float bv = merge_b[col];
                #pragma unroll
                for (int qq = 0; qq < 4; ++qq) {
                    const int row = m0 + wm * 32 + 16 * mi + lq * 4 + qq;
                    out[(size_t)row * 256 + col] = acc[mi][nj][qq] + bv;
                }
            }
        }
    }
}

// ---------------------------------------------------------------------------
// rnn-merge epilogue v2: 32x64 tiles -> 512 blocks (2/CU) for latency hiding.
// out += merged[:,0:256] @ W[:,0:256]^T (K=256, BK=64, bf16 operands, RMW).
// ---------------------------------------------------------------------------
__global__ __launch_bounds__(256) void rnn_merge(
    const short* __restrict__ merged_bf,   // (NB, 1024) bf16
    const short* __restrict__ mw_bf,       // (256, 1024) bf16
    float* __restrict__ out)               // (NB, 256)
{
    __shared__ short As[32 * 72];
    __shared__ short Bs[64 * 72];

    const int t   = threadIdx.x;
    const int w   = t >> 6, l = t & 63;
    const int wm  = w >> 1, wn = w & 1;
    const int m0  = (blockIdx.x & 127) * 32, n0 = (blockIdx.x >> 7) * 64;
    const int arow = t >> 3, ak = (t & 7) * 8;     // A: 1 short8/thread
    const int brow = t >> 2, bk = (t & 3) * 16;    // B: 2 short8/thread
    const int l15 = l & 15, lq = l >> 4;

    const short* ap = &merged_bf[(size_t)(m0 + arow) * 1024 + ak];
    const short* bp = &mw_bf    [(size_t)(n0 + brow) * 1024 + bk];

    floatx4 acc[2] = {};

    short8 a0 = *(const short8*)(ap);
    short8 b0 = *(const short8*)(bp), b1 = *(const short8*)(bp + 8);

    for (int k0 = 0; k0 < 256; k0 += 64) {
        const int kn = (k0 + 64 < 256) ? k0 + 64 : k0;
        short8 na0 = *(const short8*)(ap + kn);
        short8 nb0 = *(const short8*)(bp + kn), nb1 = *(const short8*)(bp + kn + 8);

        __syncthreads();
        *(short8*)&As[arow * 72 + ak]    = a0;
        *(short8*)&Bs[brow * 72 + bk]    = b0;
        *(short8*)&Bs[brow * 72 + bk + 8] = b1;
        __syncthreads();

        #pragma unroll
        for (int ks = 0; ks < 2; ++ks) {
            short8 af  = *(short8*)&As[(wm * 16 + l15) * 72 + ks * 32 + lq * 8];
            short8 bf0 = *(short8*)&Bs[(wn * 32 +      l15) * 72 + ks * 32 + lq * 8];
            short8 bf1 = *(short8*)&Bs[(wn * 32 + 16 + l15) * 72 + ks * 32 + lq * 8];
            acc[0] = __builtin_amdgcn_mfma_f32_16x16x32_bf16(af, bf0, acc[0], 0, 0, 0);
            acc[1] = __builtin_amdgcn_mfma_f32_16x16x32_bf16(af, bf1, acc[1], 0, 0, 0);
        }

        a0 = na0; b0 = nb0; b1 = nb1;
    }

    #pragma unroll
    for (int nj = 0; nj < 2; ++nj) {
        const int col = n0 + wn * 32 + 16 * nj + l15;
        #pragma unroll
        for (int qq = 0; qq < 4; ++qq) {
            const int row = m0 + wm * 16 + lq * 4 + qq;
            out[(size_t)row * 256 + col] += acc[nj][qq];
        }
    }
}

// ---------------------------------------------------------------------------
extern "C" void kernel_launch(void* const* d_in, const int* in_sizes, int n_in,
                              void* d_out, int out_size, void* d_ws, size_t ws_size,
                              hipStream_t stream) {
    const float* x       = (const float*)d_in[0];
    const int*   seg     = (const int*)  d_in[1];
    const float* att_w   = (const float*)d_in[2];
    const float* w_ih    = (const float*)d_in[3];
    const float* w_hh    = (const float*)d_in[4];
    const float* b_ih    = (const float*)d_in[5];
    const float* b_hh    = (const float*)d_in[6];
    const float* merge_w = (const float*)d_in[7];
    const float* merge_b = (const float*)d_in[8];
    float* out = (float*)d_out;

    // ws layout (bf16 pipeline):
    short* merged_bf   = (short*)d_ws;                       // NB*1024 shorts
    short* center_bf   = merged_bf   + (size_t)NB * 1024;    // NB*256 shorts
    short* neighbor_bf = center_bf   + (size_t)NB * DD;      // NB*256 shorts
    int*   bnd         = (int*)(neighbor_bf + (size_t)NB * DD);  // 8192 ints (4097 used)
    short* wih_bf      = (short*)(bnd + 8192);               // 196608 shorts
    short* whh_bf      = wih_bf + 196608;                    // 196608 shorts
    short* mw_bf       = whh_bf + 196608;                    // 262144 shorts

    seg_bounds<<<NBND, 256, 0, stream>>>(seg, bnd);

    seg_kernel<<<NB + WPREP, 256, 0, stream>>>(
        x, bnd, att_w, w_ih, w_hh, merge_w,
        merged_bf, center_bf, neighbor_bf, wih_bf, whh_bf, mw_bf);

    gru_and_basemerge<<<1024 + 256, 256, 0, stream>>>(
        center_bf, neighbor_bf, wih_bf, whh_bf, b_ih, b_hh,
        merged_bf, mw_bf, merge_b, out);

    rnn_merge<<<512, 256, 0, stream>>>(merged_bf, mw_bf, out);
}